// Round 1
// baseline (1137.277 us; speedup 1.0000x reference)
//
#include <hip/hip_runtime.h>
#include <hip/hip_bf16.h>

#define QQ 128
#define CC 256

typedef __attribute__((ext_vector_type(8))) _Float16 half8;
typedef __attribute__((ext_vector_type(4))) float f32x4;

union HU { half8 h; uint4 u; };

__device__ __forceinline__ unsigned short f2h_bits(float f) {
    union { _Float16 h; unsigned short u; } cv;
    cv.h = (_Float16)f;
    return cv.u;
}

// sum of v over all 256 threads; red is float[4] shared scratch
__device__ __forceinline__ float block_sum256(float v, float* red, int tid) {
#pragma unroll
    for (int off = 32; off > 0; off >>= 1)
        v += __shfl_down(v, off, 64);
    if ((tid & 63) == 0) red[tid >> 6] = v;
    __syncthreads();
    float s = red[0] + red[1] + red[2] + red[3];
    __syncthreads();
    return s;
}

// ---------------- K1: MLP head (LN -> L1 relu -> L2 relu -> L3) ----------------
// grid 128 (one block per query row), 256 threads (one per channel)
__global__ __launch_bounds__(256) void k_mlp_head(
    const float* __restrict__ cc, const float* __restrict__ ln0w, const float* __restrict__ ln0b,
    const float* __restrict__ W1, const float* __restrict__ b1,
    const float* __restrict__ W2, const float* __restrict__ b2,
    const float* __restrict__ W3, const float* __restrict__ b3,
    unsigned short* __restrict__ Mh /* [128][256] f16 bits out */)
{
    const int q = blockIdx.x, t = threadIdx.x;
    __shared__ float xs[CC], ys[CC];
    __shared__ float red[4];

    float v = cc[q * CC + t];
    float s = block_sum256(v, red, t);
    float m = s * (1.0f / CC);
    float d = v - m;
    float s2 = block_sum256(d * d, red, t);
    float rstd = rsqrtf(s2 * (1.0f / CC) + 1e-5f);
    xs[t] = d * rstd * ln0w[t] + ln0b[t];
    __syncthreads();

    // layer 1: relu(xs @ W1.T + b1)
    float acc = 0.f;
    {
        const float* w = W1 + t * CC;
#pragma unroll 8
        for (int k = 0; k < CC; k += 4) {
            float4 wv = *(const float4*)(w + k);
            acc += xs[k] * wv.x + xs[k + 1] * wv.y + xs[k + 2] * wv.z + xs[k + 3] * wv.w;
        }
    }
    ys[t] = fmaxf(acc + b1[t], 0.f);
    __syncthreads();

    // layer 2
    acc = 0.f;
    {
        const float* w = W2 + t * CC;
#pragma unroll 8
        for (int k = 0; k < CC; k += 4) {
            float4 wv = *(const float4*)(w + k);
            acc += ys[k] * wv.x + ys[k + 1] * wv.y + ys[k + 2] * wv.z + ys[k + 3] * wv.w;
        }
    }
    float x2 = fmaxf(acc + b2[t], 0.f);
    __syncthreads();
    xs[t] = x2;
    __syncthreads();

    // layer 3 (no relu)
    acc = 0.f;
    {
        const float* w = W3 + t * CC;
#pragma unroll 8
        for (int k = 0; k < CC; k += 4) {
            float4 wv = *(const float4*)(w + k);
            acc += xs[k] * wv.x + xs[k + 1] * wv.y + xs[k + 2] * wv.z + xs[k + 3] * wv.w;
        }
    }
    Mh[q * CC + t] = f2h_bits(acc + b3[t]);
}

// ---------------- K2: logits = P @ M^T via f16 MFMA, + argmax ----------------
// block = 256 threads (4 waves), tile = 128 points x 128 clusters, K=256
__global__ __launch_bounds__(256) void k_logits(
    const float* __restrict__ P, const unsigned short* __restrict__ Mh,
    float* __restrict__ out, int* __restrict__ assign, int N)
{
    __shared__ __align__(16) unsigned short Ms[QQ * CC]; // 64 KB, swizzled
    __shared__ __align__(16) unsigned short Ps[128 * CC]; // 64 KB, swizzled
    const int tid = threadIdx.x;
    const int p0 = blockIdx.x << 7;

    // stage M (f16, swizzled): 4096 chunks of 16 B
#pragma unroll
    for (int it = 0; it < 16; ++it) {
        int i = tid + (it << 8);
        int row = i >> 5, ck = i & 31;
        uint4 vd = *(reinterpret_cast<const uint4*>(Mh + (row << 8)) + ck);
        int boff = (row << 9) + ((ck << 4) ^ ((row & 7) << 4));
        *reinterpret_cast<uint4*>(reinterpret_cast<char*>(Ms) + boff) = vd;
    }
    // stage P tile, f32 -> f16, swizzled
#pragma unroll
    for (int it = 0; it < 16; ++it) {
        int i = tid + (it << 8);
        int row = i >> 5, ck = i & 31;
        int p = p0 + row;
        float4 a = make_float4(0.f, 0.f, 0.f, 0.f), b = a;
        if (p < N) {
            const float4* src = reinterpret_cast<const float4*>(P + ((size_t)p << 8)) + (ck << 1);
            a = src[0]; b = src[1];
        }
        HU pu;
        pu.h[0] = (_Float16)a.x; pu.h[1] = (_Float16)a.y;
        pu.h[2] = (_Float16)a.z; pu.h[3] = (_Float16)a.w;
        pu.h[4] = (_Float16)b.x; pu.h[5] = (_Float16)b.y;
        pu.h[6] = (_Float16)b.z; pu.h[7] = (_Float16)b.w;
        int boff = (row << 9) + ((ck << 4) ^ ((row & 7) << 4));
        *reinterpret_cast<uint4*>(reinterpret_cast<char*>(Ps) + boff) = pu.u;
    }
    __syncthreads();

    const int w = tid >> 6, l = tid & 63;
    const int lr = l & 15, lg = l >> 4;
    f32x4 acc[2][8];
#pragma unroll
    for (int i = 0; i < 2; ++i)
#pragma unroll
        for (int j = 0; j < 8; ++j) acc[i][j] = (f32x4){0.f, 0.f, 0.f, 0.f};

    const char* PsB = reinterpret_cast<const char*>(Ps);
    const char* MsB = reinterpret_cast<const char*>(Ms);
    const int r0 = (w << 5) + lr;
    const int r1 = r0 + 16;
    const int sw0 = (lr & 7) << 4; // (r0&7)==(r1&7)==(lr&7), same for B rows

#pragma unroll
    for (int kk = 0; kk < 8; ++kk) {
        const int bk = (kk << 6) + (lg << 4);
        half8 a0 = *reinterpret_cast<const half8*>(PsB + (r0 << 9) + (bk ^ sw0));
        half8 a1 = *reinterpret_cast<const half8*>(PsB + (r1 << 9) + (bk ^ sw0));
#pragma unroll
        for (int ct = 0; ct < 8; ++ct) {
            const int rb = (ct << 4) + lr;
            half8 bb = *reinterpret_cast<const half8*>(MsB + (rb << 9) + (bk ^ sw0));
            acc[0][ct] = __builtin_amdgcn_mfma_f32_16x16x32_f16(a0, bb, acc[0][ct], 0, 0, 0);
            acc[1][ct] = __builtin_amdgcn_mfma_f32_16x16x32_f16(a1, bb, acc[1][ct], 0, 0, 0);
        }
    }

    // store logits + argmax (C/D layout: col = lane&15, row = (lane>>4)*4 + reg)
#pragma unroll
    for (int rt = 0; rt < 2; ++rt) {
#pragma unroll
        for (int j = 0; j < 4; ++j) {
            const int row = (w << 5) + (rt << 4) + (lg << 2) + j;
            const int p = p0 + row;
            float bv = -3.402823e38f; int bi = 0;
            if (p < N) {
                float* orow = out + ((size_t)p << 7);
#pragma unroll
                for (int ct = 0; ct < 8; ++ct) {
                    float vv = acc[rt][ct][j];
                    int cidx = (ct << 4) + lr;
                    orow[cidx] = vv;
                    if (vv > bv) { bv = vv; bi = cidx; } // cidx ascending -> keeps lowest on tie
                }
            }
            // reduce over the 16 lanes holding this row's 128 columns
#pragma unroll
            for (int msk = 1; msk < 16; msk <<= 1) {
                float ov = __shfl_xor(bv, msk, 64);
                int oi = __shfl_xor(bi, msk, 64);
                if (ov > bv || (ov == bv && oi < bi)) { bv = ov; bi = oi; }
            }
            if (lr == 0 && p < N) assign[p] = bi;
        }
    }
}

// ---------------- K3: segment sum by assign, LDS bins ----------------
// 256 blocks x 256 threads; thread t owns channel t; all threads walk same p
__global__ __launch_bounds__(256) void k_segsum(
    const float* __restrict__ P, const int* __restrict__ assign,
    float* __restrict__ cm, int N)
{
    __shared__ float bins[QQ * CC]; // 128 KB
    const int t = threadIdx.x;
    for (int i = t; i < QQ * CC; i += 256) bins[i] = 0.f;
    __syncthreads();

#pragma unroll 16
    for (int p = blockIdx.x; p < N; p += gridDim.x) {
        int a = assign[p];                       // broadcast within wave
        float v = P[(size_t)p * CC + t];         // coalesced
        bins[a * CC + t] += v;                   // exclusive per-thread channel
    }
    __syncthreads();
    for (int i = t; i < QQ * CC; i += 256) {
        float b = bins[i];
        if (b != 0.f) atomicAdd(&cm[i], b);
        else atomicAdd(&cm[i], 0.f); // keep deterministic op count (cheap; could skip)
    }
}

// ---------------- K4: bottleneck LN -> Wb -> LN, + residual ----------------
__global__ __launch_bounds__(256) void k_bottleneck(
    const float* __restrict__ cm,
    const float* __restrict__ lnb1w, const float* __restrict__ lnb1b,
    const float* __restrict__ Wb,
    const float* __restrict__ lnb2w, const float* __restrict__ lnb2b,
    const float* __restrict__ cc, float* __restrict__ out2)
{
    const int q = blockIdx.x, t = threadIdx.x;
    __shared__ float xs[CC];
    __shared__ float red[4];

    float v = cm[q * CC + t];
    float s = block_sum256(v, red, t);
    float m = s * (1.0f / CC);
    float d = v - m;
    float s2 = block_sum256(d * d, red, t);
    float rstd = rsqrtf(s2 * (1.0f / CC) + 1e-5f);
    xs[t] = d * rstd * lnb1w[t] + lnb1b[t];
    __syncthreads();

    float acc = 0.f;
    {
        const float* w = Wb + t * CC;
#pragma unroll 8
        for (int k = 0; k < CC; k += 4) {
            float4 wv = *(const float4*)(w + k);
            acc += xs[k] * wv.x + xs[k + 1] * wv.y + xs[k + 2] * wv.z + xs[k + 3] * wv.w;
        }
    }
    float zs = block_sum256(acc, red, t);
    float zm = zs * (1.0f / CC);
    float zd = acc - zm;
    float zs2 = block_sum256(zd * zd, red, t);
    float zr = rsqrtf(zs2 * (1.0f / CC) + 1e-5f);
    out2[q * CC + t] = cc[q * CC + t] + zd * zr * lnb2w[t] + lnb2b[t];
}

extern "C" void kernel_launch(void* const* d_in, const int* in_sizes, int n_in,
                              void* d_out, int out_size, void* d_ws, size_t ws_size,
                              hipStream_t stream) {
    const float* cc   = (const float*)d_in[0];
    const float* P    = (const float*)d_in[1];
    const float* ln0w = (const float*)d_in[2];
    const float* ln0b = (const float*)d_in[3];
    const float* W1   = (const float*)d_in[4];
    const float* b1   = (const float*)d_in[5];
    const float* W2   = (const float*)d_in[6];
    const float* b2   = (const float*)d_in[7];
    const float* W3   = (const float*)d_in[8];
    const float* b3   = (const float*)d_in[9];
    const float* lnb1w = (const float*)d_in[10];
    const float* lnb1b = (const float*)d_in[11];
    const float* Wb   = (const float*)d_in[12];
    const float* lnb2w = (const float*)d_in[13];
    const float* lnb2b = (const float*)d_in[14];

    const int N = in_sizes[1] / CC;

    char* ws = (char*)d_ws;
    unsigned short* Mh = (unsigned short*)ws;               // 128*256*2 = 65536 B
    float* cm = (float*)(ws + 65536);                       // 131072 B
    int* assign = (int*)(ws + 65536 + 131072);              // 4*N B

    float* logits = (float*)d_out;                          // [N][128]
    float* out2 = (float*)d_out + (size_t)N * QQ;           // [128][256]

    hipMemsetAsync(cm, 0, QQ * CC * sizeof(float), stream);

    k_mlp_head<<<QQ, 256, 0, stream>>>(cc, ln0w, ln0b, W1, b1, W2, b2, W3, b3, Mh);

    int nblk = (N + 127) >> 7;
    k_logits<<<nblk, 256, 0, stream>>>(P, Mh, logits, assign, N);

    k_segsum<<<256, 256, 0, stream>>>(P, assign, cm, N);

    k_bottleneck<<<QQ, 256, 0, stream>>>(cm, lnb1w, lnb1b, Wb, lnb2w, lnb2b, cc, out2);
}

// Round 2
// 978.614 us; speedup vs baseline: 1.1621x; 1.1621x over previous
//
#include <hip/hip_runtime.h>
#include <hip/hip_bf16.h>

#define QQ 128
#define CC 256

typedef __attribute__((ext_vector_type(8))) _Float16 half8;
typedef __attribute__((ext_vector_type(4))) float f32x4;

union HU { half8 h; uint4 u; };

__device__ __forceinline__ unsigned short f2h_bits(float f) {
    union { _Float16 h; unsigned short u; } cv;
    cv.h = (_Float16)f;
    return cv.u;
}

// sum of v over all 256 threads; red is float[4] shared scratch
__device__ __forceinline__ float block_sum256(float v, float* red, int tid) {
#pragma unroll
    for (int off = 32; off > 0; off >>= 1)
        v += __shfl_down(v, off, 64);
    if ((tid & 63) == 0) red[tid >> 6] = v;
    __syncthreads();
    float s = red[0] + red[1] + red[2] + red[3];
    __syncthreads();
    return s;
}

// ---------------- K1: MLP head (LN -> L1 relu -> L2 relu -> L3) ----------------
// grid 128 (one block per query row), 256 threads (one per channel)
__global__ __launch_bounds__(256) void k_mlp_head(
    const float* __restrict__ cc, const float* __restrict__ ln0w, const float* __restrict__ ln0b,
    const float* __restrict__ W1, const float* __restrict__ b1,
    const float* __restrict__ W2, const float* __restrict__ b2,
    const float* __restrict__ W3, const float* __restrict__ b3,
    unsigned short* __restrict__ Mh /* [128][256] f16 bits out */)
{
    const int q = blockIdx.x, t = threadIdx.x;
    __shared__ float xs[CC], ys[CC];
    __shared__ float red[4];

    float v = cc[q * CC + t];
    float s = block_sum256(v, red, t);
    float m = s * (1.0f / CC);
    float d = v - m;
    float s2 = block_sum256(d * d, red, t);
    float rstd = rsqrtf(s2 * (1.0f / CC) + 1e-5f);
    xs[t] = d * rstd * ln0w[t] + ln0b[t];
    __syncthreads();

    // layer 1: relu(xs @ W1.T + b1)
    float acc = 0.f;
    {
        const float* w = W1 + t * CC;
#pragma unroll 8
        for (int k = 0; k < CC; k += 4) {
            float4 wv = *(const float4*)(w + k);
            acc += xs[k] * wv.x + xs[k + 1] * wv.y + xs[k + 2] * wv.z + xs[k + 3] * wv.w;
        }
    }
    ys[t] = fmaxf(acc + b1[t], 0.f);
    __syncthreads();

    // layer 2
    acc = 0.f;
    {
        const float* w = W2 + t * CC;
#pragma unroll 8
        for (int k = 0; k < CC; k += 4) {
            float4 wv = *(const float4*)(w + k);
            acc += ys[k] * wv.x + ys[k + 1] * wv.y + ys[k + 2] * wv.z + ys[k + 3] * wv.w;
        }
    }
    float x2 = fmaxf(acc + b2[t], 0.f);
    __syncthreads();
    xs[t] = x2;
    __syncthreads();

    // layer 3 (no relu)
    acc = 0.f;
    {
        const float* w = W3 + t * CC;
#pragma unroll 8
        for (int k = 0; k < CC; k += 4) {
            float4 wv = *(const float4*)(w + k);
            acc += xs[k] * wv.x + xs[k + 1] * wv.y + xs[k + 2] * wv.z + xs[k + 3] * wv.w;
        }
    }
    Mh[q * CC + t] = f2h_bits(acc + b3[t]);
}

// ---------------- K2: logits = P @ M^T via f16 MFMA, + argmax ----------------
// block = 256 threads (4 waves), tile = 128 points x 128 clusters, K=256
__global__ __launch_bounds__(256) void k_logits(
    const float* __restrict__ P, const unsigned short* __restrict__ Mh,
    float* __restrict__ out, int* __restrict__ assign, int N)
{
    __shared__ __align__(16) unsigned short Ms[QQ * CC]; // 64 KB, swizzled
    __shared__ __align__(16) unsigned short Ps[128 * CC]; // 64 KB, swizzled
    const int tid = threadIdx.x;
    const int p0 = blockIdx.x << 7;

    // stage M (f16, swizzled): 4096 chunks of 16 B
#pragma unroll
    for (int it = 0; it < 16; ++it) {
        int i = tid + (it << 8);
        int row = i >> 5, ck = i & 31;
        uint4 vd = *(reinterpret_cast<const uint4*>(Mh + (row << 8)) + ck);
        int boff = (row << 9) + ((ck << 4) ^ ((row & 7) << 4));
        *reinterpret_cast<uint4*>(reinterpret_cast<char*>(Ms) + boff) = vd;
    }
    // stage P tile, f32 -> f16, swizzled
#pragma unroll
    for (int it = 0; it < 16; ++it) {
        int i = tid + (it << 8);
        int row = i >> 5, ck = i & 31;
        int p = p0 + row;
        float4 a = make_float4(0.f, 0.f, 0.f, 0.f), b = a;
        if (p < N) {
            const float4* src = reinterpret_cast<const float4*>(P + ((size_t)p << 8)) + (ck << 1);
            a = src[0]; b = src[1];
        }
        HU pu;
        pu.h[0] = (_Float16)a.x; pu.h[1] = (_Float16)a.y;
        pu.h[2] = (_Float16)a.z; pu.h[3] = (_Float16)a.w;
        pu.h[4] = (_Float16)b.x; pu.h[5] = (_Float16)b.y;
        pu.h[6] = (_Float16)b.z; pu.h[7] = (_Float16)b.w;
        int boff = (row << 9) + ((ck << 4) ^ ((row & 7) << 4));
        *reinterpret_cast<uint4*>(reinterpret_cast<char*>(Ps) + boff) = pu.u;
    }
    __syncthreads();

    const int w = tid >> 6, l = tid & 63;
    const int lr = l & 15, lg = l >> 4;
    f32x4 acc[2][8];
#pragma unroll
    for (int i = 0; i < 2; ++i)
#pragma unroll
        for (int j = 0; j < 8; ++j) acc[i][j] = (f32x4){0.f, 0.f, 0.f, 0.f};

    const char* PsB = reinterpret_cast<const char*>(Ps);
    const char* MsB = reinterpret_cast<const char*>(Ms);
    const int r0 = (w << 5) + lr;
    const int r1 = r0 + 16;
    const int sw0 = (lr & 7) << 4; // (r0&7)==(r1&7)==(lr&7), same for B rows

#pragma unroll
    for (int kk = 0; kk < 8; ++kk) {
        const int bk = (kk << 6) + (lg << 4);
        half8 a0 = *reinterpret_cast<const half8*>(PsB + (r0 << 9) + (bk ^ sw0));
        half8 a1 = *reinterpret_cast<const half8*>(PsB + (r1 << 9) + (bk ^ sw0));
#pragma unroll
        for (int ct = 0; ct < 8; ++ct) {
            const int rb = (ct << 4) + lr;
            half8 bb = *reinterpret_cast<const half8*>(MsB + (rb << 9) + (bk ^ sw0));
            acc[0][ct] = __builtin_amdgcn_mfma_f32_16x16x32_f16(a0, bb, acc[0][ct], 0, 0, 0);
            acc[1][ct] = __builtin_amdgcn_mfma_f32_16x16x32_f16(a1, bb, acc[1][ct], 0, 0, 0);
        }
    }

    // store logits + argmax (C/D layout: col = lane&15, row = (lane>>4)*4 + reg)
#pragma unroll
    for (int rt = 0; rt < 2; ++rt) {
#pragma unroll
        for (int j = 0; j < 4; ++j) {
            const int row = (w << 5) + (rt << 4) + (lg << 2) + j;
            const int p = p0 + row;
            float bv = -3.402823e38f; int bi = 0;
            if (p < N) {
                float* orow = out + ((size_t)p << 7);
#pragma unroll
                for (int ct = 0; ct < 8; ++ct) {
                    float vv = acc[rt][ct][j];
                    int cidx = (ct << 4) + lr;
                    orow[cidx] = vv;
                    if (vv > bv) { bv = vv; bi = cidx; } // cidx ascending -> keeps lowest on tie
                }
            }
            // reduce over the 16 lanes holding this row's 128 columns
#pragma unroll
            for (int msk = 1; msk < 16; msk <<= 1) {
                float ov = __shfl_xor(bv, msk, 64);
                int oi = __shfl_xor(bi, msk, 64);
                if (ov > bv || (ov == bv && oi < bi)) { bv = ov; bi = oi; }
            }
            if (lr == 0 && p < N) assign[p] = bi;
        }
    }
}

// ---------------- K3: segment sum by assign, LDS bins (wave-per-point, ds_add) --
// 256 blocks x 256 threads (4 waves). Wave w of block b owns points
// p = b*4 + w + 1024*i. Lane l loads float4 channels [4l..4l+3].
// Bins are component-split [4][QQ][64] so ds_add addresses hit bank = l&31
// (2-way aliasing = free). LDS f32 atomics are fire-and-forget: no RMW chain.
__global__ __launch_bounds__(256) void k_segsum(
    const float* __restrict__ P, const int* __restrict__ assign,
    float* __restrict__ cm, int N)
{
    __shared__ float bins[4][QQ * 64]; // 128 KB
    const int t = threadIdx.x;
    const int w = t >> 6, l = t & 63;

    for (int i = t; i < 4 * QQ * 64; i += 256) ((float*)bins)[i] = 0.f;
    __syncthreads();

    const int stride = 1024;               // 256 blocks * 4 waves
    const int base = (blockIdx.x << 2) + w;
    const size_t c4 = (size_t)(l << 2);    // channel group start

    int p = base;
    // 8-deep pipelined main loop: 8 float4 loads in flight per wave
    for (; p + 7 * stride < N; p += 8 * stride) {
        float4 v[8]; int a[8];
#pragma unroll
        for (int k = 0; k < 8; ++k) {
            int pp = p + k * stride;
            v[k] = *reinterpret_cast<const float4*>(P + (size_t)pp * CC + c4);
            a[k] = assign[pp];
        }
#pragma unroll
        for (int k = 0; k < 8; ++k) {
            const int bo = a[k] * 64 + l;
            unsafeAtomicAdd(&bins[0][bo], v[k].x);
            unsafeAtomicAdd(&bins[1][bo], v[k].y);
            unsafeAtomicAdd(&bins[2][bo], v[k].z);
            unsafeAtomicAdd(&bins[3][bo], v[k].w);
        }
    }
    for (; p < N; p += stride) {
        float4 v = *reinterpret_cast<const float4*>(P + (size_t)p * CC + c4);
        int a = assign[p];
        const int bo = a * 64 + l;
        unsafeAtomicAdd(&bins[0][bo], v.x);
        unsafeAtomicAdd(&bins[1][bo], v.y);
        unsafeAtomicAdd(&bins[2][bo], v.z);
        unsafeAtomicAdd(&bins[3][bo], v.w);
    }
    __syncthreads();

    // flush: channel c of cluster a lives at bins[c&3][a*64 + (c>>2)]
    for (int i = t; i < QQ * CC; i += 256) {
        int a = i >> 8, c = i & 255;
        float b = bins[c & 3][a * 64 + (c >> 2)];
        if (b != 0.f) unsafeAtomicAdd(&cm[i], b);
    }
}

// ---------------- K4: bottleneck LN -> Wb -> LN, + residual ----------------
__global__ __launch_bounds__(256) void k_bottleneck(
    const float* __restrict__ cm,
    const float* __restrict__ lnb1w, const float* __restrict__ lnb1b,
    const float* __restrict__ Wb,
    const float* __restrict__ lnb2w, const float* __restrict__ lnb2b,
    const float* __restrict__ cc, float* __restrict__ out2)
{
    const int q = blockIdx.x, t = threadIdx.x;
    __shared__ float xs[CC];
    __shared__ float red[4];

    float v = cm[q * CC + t];
    float s = block_sum256(v, red, t);
    float m = s * (1.0f / CC);
    float d = v - m;
    float s2 = block_sum256(d * d, red, t);
    float rstd = rsqrtf(s2 * (1.0f / CC) + 1e-5f);
    xs[t] = d * rstd * lnb1w[t] + lnb1b[t];
    __syncthreads();

    float acc = 0.f;
    {
        const float* w = Wb + t * CC;
#pragma unroll 8
        for (int k = 0; k < CC; k += 4) {
            float4 wv = *(const float4*)(w + k);
            acc += xs[k] * wv.x + xs[k + 1] * wv.y + xs[k + 2] * wv.z + xs[k + 3] * wv.w;
        }
    }
    float zs = block_sum256(acc, red, t);
    float zm = zs * (1.0f / CC);
    float zd = acc - zm;
    float zs2 = block_sum256(zd * zd, red, t);
    float zr = rsqrtf(zs2 * (1.0f / CC) + 1e-5f);
    out2[q * CC + t] = cc[q * CC + t] + zd * zr * lnb2w[t] + lnb2b[t];
}

extern "C" void kernel_launch(void* const* d_in, const int* in_sizes, int n_in,
                              void* d_out, int out_size, void* d_ws, size_t ws_size,
                              hipStream_t stream) {
    const float* cc   = (const float*)d_in[0];
    const float* P    = (const float*)d_in[1];
    const float* ln0w = (const float*)d_in[2];
    const float* ln0b = (const float*)d_in[3];
    const float* W1   = (const float*)d_in[4];
    const float* b1   = (const float*)d_in[5];
    const float* W2   = (const float*)d_in[6];
    const float* b2   = (const float*)d_in[7];
    const float* W3   = (const float*)d_in[8];
    const float* b3   = (const float*)d_in[9];
    const float* lnb1w = (const float*)d_in[10];
    const float* lnb1b = (const float*)d_in[11];
    const float* Wb   = (const float*)d_in[12];
    const float* lnb2w = (const float*)d_in[13];
    const float* lnb2b = (const float*)d_in[14];

    const int N = in_sizes[1] / CC;

    char* ws = (char*)d_ws;
    unsigned short* Mh = (unsigned short*)ws;               // 128*256*2 = 65536 B
    float* cm = (float*)(ws + 65536);                       // 131072 B
    int* assign = (int*)(ws + 65536 + 131072);              // 4*N B

    float* logits = (float*)d_out;                          // [N][128]
    float* out2 = (float*)d_out + (size_t)N * QQ;           // [128][256]

    hipMemsetAsync(cm, 0, QQ * CC * sizeof(float), stream);

    k_mlp_head<<<QQ, 256, 0, stream>>>(cc, ln0w, ln0b, W1, b1, W2, b2, W3, b3, Mh);

    int nblk = (N + 127) >> 7;
    k_logits<<<nblk, 256, 0, stream>>>(P, Mh, logits, assign, N);

    k_segsum<<<256, 256, 0, stream>>>(P, assign, cm, N);

    k_bottleneck<<<QQ, 256, 0, stream>>>(cm, lnb1w, lnb1b, Wb, lnb2w, lnb2b, cc, out2);
}

// Round 3
// 964.502 us; speedup vs baseline: 1.1791x; 1.0146x over previous
//
#include <hip/hip_runtime.h>
#include <hip/hip_bf16.h>

#define QQ 128
#define CC 256

typedef __attribute__((ext_vector_type(8))) _Float16 half8;
typedef __attribute__((ext_vector_type(4))) float f32x4;

union HU { half8 h; uint4 u; };

__device__ __forceinline__ unsigned short f2h_bits(float f) {
    union { _Float16 h; unsigned short u; } cv;
    cv.h = (_Float16)f;
    return cv.u;
}

// sum of v over all 256 threads; red is float[4] shared scratch
__device__ __forceinline__ float block_sum256(float v, float* red, int tid) {
#pragma unroll
    for (int off = 32; off > 0; off >>= 1)
        v += __shfl_down(v, off, 64);
    if ((tid & 63) == 0) red[tid >> 6] = v;
    __syncthreads();
    float s = red[0] + red[1] + red[2] + red[3];
    __syncthreads();
    return s;
}

// ---------------- K1: MLP head (LN -> L1 relu -> L2 relu -> L3) ----------------
// grid 128 (one block per query row), 256 threads (one per channel)
__global__ __launch_bounds__(256) void k_mlp_head(
    const float* __restrict__ cc, const float* __restrict__ ln0w, const float* __restrict__ ln0b,
    const float* __restrict__ W1, const float* __restrict__ b1,
    const float* __restrict__ W2, const float* __restrict__ b2,
    const float* __restrict__ W3, const float* __restrict__ b3,
    unsigned short* __restrict__ Mh /* [128][256] f16 bits out */)
{
    const int q = blockIdx.x, t = threadIdx.x;
    __shared__ float xs[CC], ys[CC];
    __shared__ float red[4];

    float v = cc[q * CC + t];
    float s = block_sum256(v, red, t);
    float m = s * (1.0f / CC);
    float d = v - m;
    float s2 = block_sum256(d * d, red, t);
    float rstd = rsqrtf(s2 * (1.0f / CC) + 1e-5f);
    xs[t] = d * rstd * ln0w[t] + ln0b[t];
    __syncthreads();

    // layer 1: relu(xs @ W1.T + b1)
    float acc = 0.f;
    {
        const float* w = W1 + t * CC;
#pragma unroll 8
        for (int k = 0; k < CC; k += 4) {
            float4 wv = *(const float4*)(w + k);
            acc += xs[k] * wv.x + xs[k + 1] * wv.y + xs[k + 2] * wv.z + xs[k + 3] * wv.w;
        }
    }
    ys[t] = fmaxf(acc + b1[t], 0.f);
    __syncthreads();

    // layer 2
    acc = 0.f;
    {
        const float* w = W2 + t * CC;
#pragma unroll 8
        for (int k = 0; k < CC; k += 4) {
            float4 wv = *(const float4*)(w + k);
            acc += ys[k] * wv.x + ys[k + 1] * wv.y + ys[k + 2] * wv.z + ys[k + 3] * wv.w;
        }
    }
    float x2 = fmaxf(acc + b2[t], 0.f);
    __syncthreads();
    xs[t] = x2;
    __syncthreads();

    // layer 3 (no relu)
    acc = 0.f;
    {
        const float* w = W3 + t * CC;
#pragma unroll 8
        for (int k = 0; k < CC; k += 4) {
            float4 wv = *(const float4*)(w + k);
            acc += xs[k] * wv.x + xs[k + 1] * wv.y + xs[k + 2] * wv.z + xs[k + 3] * wv.w;
        }
    }
    Mh[q * CC + t] = f2h_bits(acc + b3[t]);
}

// ---------------- K2: logits = P @ M^T via f16 MFMA, + argmax ----------------
// block = 256 threads (4 waves), tile = 128 points x 128 clusters, K=256
__global__ __launch_bounds__(256) void k_logits(
    const float* __restrict__ P, const unsigned short* __restrict__ Mh,
    float* __restrict__ out, int* __restrict__ assign, int N)
{
    __shared__ __align__(16) unsigned short Ms[QQ * CC]; // 64 KB, swizzled
    __shared__ __align__(16) unsigned short Ps[128 * CC]; // 64 KB, swizzled
    const int tid = threadIdx.x;
    const int p0 = blockIdx.x << 7;

    // stage M (f16, swizzled): 4096 chunks of 16 B
#pragma unroll
    for (int it = 0; it < 16; ++it) {
        int i = tid + (it << 8);
        int row = i >> 5, ck = i & 31;
        uint4 vd = *(reinterpret_cast<const uint4*>(Mh + (row << 8)) + ck);
        int boff = (row << 9) + ((ck << 4) ^ ((row & 7) << 4));
        *reinterpret_cast<uint4*>(reinterpret_cast<char*>(Ms) + boff) = vd;
    }
    // stage P tile, f32 -> f16, swizzled
#pragma unroll
    for (int it = 0; it < 16; ++it) {
        int i = tid + (it << 8);
        int row = i >> 5, ck = i & 31;
        int p = p0 + row;
        float4 a = make_float4(0.f, 0.f, 0.f, 0.f), b = a;
        if (p < N) {
            const float4* src = reinterpret_cast<const float4*>(P + ((size_t)p << 8)) + (ck << 1);
            a = src[0]; b = src[1];
        }
        HU pu;
        pu.h[0] = (_Float16)a.x; pu.h[1] = (_Float16)a.y;
        pu.h[2] = (_Float16)a.z; pu.h[3] = (_Float16)a.w;
        pu.h[4] = (_Float16)b.x; pu.h[5] = (_Float16)b.y;
        pu.h[6] = (_Float16)b.z; pu.h[7] = (_Float16)b.w;
        int boff = (row << 9) + ((ck << 4) ^ ((row & 7) << 4));
        *reinterpret_cast<uint4*>(reinterpret_cast<char*>(Ps) + boff) = pu.u;
    }
    __syncthreads();

    const int w = tid >> 6, l = tid & 63;
    const int lr = l & 15, lg = l >> 4;
    f32x4 acc[2][8];
#pragma unroll
    for (int i = 0; i < 2; ++i)
#pragma unroll
        for (int j = 0; j < 8; ++j) acc[i][j] = (f32x4){0.f, 0.f, 0.f, 0.f};

    const char* PsB = reinterpret_cast<const char*>(Ps);
    const char* MsB = reinterpret_cast<const char*>(Ms);
    const int r0 = (w << 5) + lr;
    const int r1 = r0 + 16;
    const int sw0 = (lr & 7) << 4; // (r0&7)==(r1&7)==(lr&7), same for B rows

#pragma unroll
    for (int kk = 0; kk < 8; ++kk) {
        const int bk = (kk << 6) + (lg << 4);
        half8 a0 = *reinterpret_cast<const half8*>(PsB + (r0 << 9) + (bk ^ sw0));
        half8 a1 = *reinterpret_cast<const half8*>(PsB + (r1 << 9) + (bk ^ sw0));
#pragma unroll
        for (int ct = 0; ct < 8; ++ct) {
            const int rb = (ct << 4) + lr;
            half8 bb = *reinterpret_cast<const half8*>(MsB + (rb << 9) + (bk ^ sw0));
            acc[0][ct] = __builtin_amdgcn_mfma_f32_16x16x32_f16(a0, bb, acc[0][ct], 0, 0, 0);
            acc[1][ct] = __builtin_amdgcn_mfma_f32_16x16x32_f16(a1, bb, acc[1][ct], 0, 0, 0);
        }
    }

    // store logits + argmax (C/D layout: col = lane&15, row = (lane>>4)*4 + reg)
#pragma unroll
    for (int rt = 0; rt < 2; ++rt) {
#pragma unroll
        for (int j = 0; j < 4; ++j) {
            const int row = (w << 5) + (rt << 4) + (lg << 2) + j;
            const int p = p0 + row;
            float bv = -3.402823e38f; int bi = 0;
            if (p < N) {
                float* orow = out + ((size_t)p << 7);
#pragma unroll
                for (int ct = 0; ct < 8; ++ct) {
                    float vv = acc[rt][ct][j];
                    int cidx = (ct << 4) + lr;
                    orow[cidx] = vv;
                    if (vv > bv) { bv = vv; bi = cidx; } // cidx ascending -> keeps lowest on tie
                }
            }
            // reduce over the 16 lanes holding this row's 128 columns
#pragma unroll
            for (int msk = 1; msk < 16; msk <<= 1) {
                float ov = __shfl_xor(bv, msk, 64);
                int oi = __shfl_xor(bi, msk, 64);
                if (ov > bv || (ov == bv && oi < bi)) { bv = ov; bi = oi; }
            }
            if (lr == 0 && p < N) assign[p] = bi;
        }
    }
}

// ---------------- K3: segment sum by assign, LDS bins (wave-per-point, ds_add) --
// nparts blocks x 256 threads (4 waves). Wave w of block b owns points
// p = b*4 + w + (4*gridDim)*i. Lane l loads float4 channels [4l..4l+3].
// Bins are component-split [4][QQ][64] so ds_add addresses hit bank = l&31
// (2-way aliasing = free). LDS f32 atomics are fire-and-forget: no RMW chain.
// Flush: plain coalesced stores to a per-block partial buffer (no global
// atomics -> no cross-block cacheline contention). partial[b][q*256+c].
__global__ __launch_bounds__(256) void k_segsum(
    const float* __restrict__ P, const int* __restrict__ assign,
    float* __restrict__ partial, int N)
{
    __shared__ float bins[4][QQ * 64]; // 128 KB
    const int t = threadIdx.x;
    const int w = t >> 6, l = t & 63;

    for (int i = t; i < 4 * QQ * 64; i += 256) ((float*)bins)[i] = 0.f;
    __syncthreads();

    const int stride = gridDim.x << 2;     // blocks * 4 waves
    const int base = (blockIdx.x << 2) + w;
    const size_t c4 = (size_t)(l << 2);    // channel group start

    int p = base;
    // 8-deep pipelined main loop: 8 float4 loads in flight per wave
    for (; p + 7 * stride < N; p += 8 * stride) {
        float4 v[8]; int a[8];
#pragma unroll
        for (int k = 0; k < 8; ++k) {
            int pp = p + k * stride;
            v[k] = *reinterpret_cast<const float4*>(P + (size_t)pp * CC + c4);
            a[k] = assign[pp];
        }
#pragma unroll
        for (int k = 0; k < 8; ++k) {
            const int bo = a[k] * 64 + l;
            unsafeAtomicAdd(&bins[0][bo], v[k].x);
            unsafeAtomicAdd(&bins[1][bo], v[k].y);
            unsafeAtomicAdd(&bins[2][bo], v[k].z);
            unsafeAtomicAdd(&bins[3][bo], v[k].w);
        }
    }
    for (; p < N; p += stride) {
        float4 v = *reinterpret_cast<const float4*>(P + (size_t)p * CC + c4);
        int a = assign[p];
        const int bo = a * 64 + l;
        unsafeAtomicAdd(&bins[0][bo], v.x);
        unsafeAtomicAdd(&bins[1][bo], v.y);
        unsafeAtomicAdd(&bins[2][bo], v.z);
        unsafeAtomicAdd(&bins[3][bo], v.w);
    }
    __syncthreads();

    // flush de-swizzled: channel c of cluster a lives at bins[c&3][a*64+(c>>2)]
    float* my = partial + (size_t)blockIdx.x * (QQ * CC);
    for (int i = t; i < QQ * CC; i += 256) {
        int a = i >> 8, c = i & 255;
        my[i] = bins[c & 3][a * 64 + (c >> 2)];
    }
}

// ---------------- K4: reduce partials + bottleneck LN -> Wb -> LN, + residual --
__global__ __launch_bounds__(256) void k_bottleneck(
    const float* __restrict__ partial, int nparts,
    const float* __restrict__ lnb1w, const float* __restrict__ lnb1b,
    const float* __restrict__ Wb,
    const float* __restrict__ lnb2w, const float* __restrict__ lnb2b,
    const float* __restrict__ cc, float* __restrict__ out2)
{
    const int q = blockIdx.x, t = threadIdx.x;
    __shared__ float xs[CC];
    __shared__ float red[4];

    // reduce cluster-memory for (q, t) over per-block partials; coalesced
    float v = 0.f;
    {
        const float* src = partial + (size_t)q * CC + t;
        int part = 0;
        for (; part + 7 < nparts; part += 8) {
            float s0 = src[(size_t)(part + 0) * (QQ * CC)];
            float s1 = src[(size_t)(part + 1) * (QQ * CC)];
            float s2 = src[(size_t)(part + 2) * (QQ * CC)];
            float s3 = src[(size_t)(part + 3) * (QQ * CC)];
            float s4 = src[(size_t)(part + 4) * (QQ * CC)];
            float s5 = src[(size_t)(part + 5) * (QQ * CC)];
            float s6 = src[(size_t)(part + 6) * (QQ * CC)];
            float s7 = src[(size_t)(part + 7) * (QQ * CC)];
            v += ((s0 + s1) + (s2 + s3)) + ((s4 + s5) + (s6 + s7));
        }
        for (; part < nparts; ++part)
            v += src[(size_t)part * (QQ * CC)];
    }

    float s = block_sum256(v, red, t);
    float m = s * (1.0f / CC);
    float d = v - m;
    float s2 = block_sum256(d * d, red, t);
    float rstd = rsqrtf(s2 * (1.0f / CC) + 1e-5f);
    xs[t] = d * rstd * lnb1w[t] + lnb1b[t];
    __syncthreads();

    float acc = 0.f;
    {
        const float* wp = Wb + t * CC;
#pragma unroll 8
        for (int k = 0; k < CC; k += 4) {
            float4 wv = *(const float4*)(wp + k);
            acc += xs[k] * wv.x + xs[k + 1] * wv.y + xs[k + 2] * wv.z + xs[k + 3] * wv.w;
        }
    }
    float zs = block_sum256(acc, red, t);
    float zm = zs * (1.0f / CC);
    float zd = acc - zm;
    float zs2 = block_sum256(zd * zd, red, t);
    float zr = rsqrtf(zs2 * (1.0f / CC) + 1e-5f);
    out2[q * CC + t] = cc[q * CC + t] + zd * zr * lnb2w[t] + lnb2b[t];
}

extern "C" void kernel_launch(void* const* d_in, const int* in_sizes, int n_in,
                              void* d_out, int out_size, void* d_ws, size_t ws_size,
                              hipStream_t stream) {
    const float* cc   = (const float*)d_in[0];
    const float* P    = (const float*)d_in[1];
    const float* ln0w = (const float*)d_in[2];
    const float* ln0b = (const float*)d_in[3];
    const float* W1   = (const float*)d_in[4];
    const float* b1   = (const float*)d_in[5];
    const float* W2   = (const float*)d_in[6];
    const float* b2   = (const float*)d_in[7];
    const float* W3   = (const float*)d_in[8];
    const float* b3   = (const float*)d_in[9];
    const float* lnb1w = (const float*)d_in[10];
    const float* lnb1b = (const float*)d_in[11];
    const float* Wb   = (const float*)d_in[12];
    const float* lnb2w = (const float*)d_in[13];
    const float* lnb2b = (const float*)d_in[14];

    const int N = in_sizes[1] / CC;

    char* ws = (char*)d_ws;
    unsigned short* Mh = (unsigned short*)ws;               // 65536 B
    size_t off = 65536;
    int* assign = (int*)(ws + off);                         // 4*N B
    off += ((size_t)4 * N + 1023) & ~(size_t)1023;
    float* partial = (float*)(ws + off);                    // nparts * 128 KB

    const size_t part_bytes = (size_t)QQ * CC * sizeof(float);
    size_t avail = (ws_size > off) ? (ws_size - off) : 0;
    int nparts = (int)(avail / part_bytes);
    if (nparts > 256) nparts = 256;
    if (nparts < 1) nparts = 1;

    float* logits = (float*)d_out;                          // [N][128]
    float* out2 = (float*)d_out + (size_t)N * QQ;           // [128][256]

    k_mlp_head<<<QQ, 256, 0, stream>>>(cc, ln0w, ln0b, W1, b1, W2, b2, W3, b3, Mh);

    int nblk = (N + 127) >> 7;
    k_logits<<<nblk, 256, 0, stream>>>(P, Mh, logits, assign, N);

    k_segsum<<<nparts, 256, 0, stream>>>(P, assign, partial, N);

    k_bottleneck<<<QQ, 256, 0, stream>>>(partial, nparts, lnb1w, lnb1b, Wb, lnb2w, lnb2b, cc, out2);
}

// Round 4
// 352.904 us; speedup vs baseline: 3.2226x; 2.7330x over previous
//
#include <hip/hip_runtime.h>
#include <hip/hip_bf16.h>

#define QQ 128
#define CC 256
#define GG 8      // clusters per group
#define NGRP 16   // 128/GG
#define HH 32     // range splits; segsum grid = NGRP*HH = 512

typedef __attribute__((ext_vector_type(8))) _Float16 half8;
typedef __attribute__((ext_vector_type(4))) float f32x4;

union HU { half8 h; uint4 u; };

__device__ __forceinline__ unsigned short f2h_bits(float f) {
    union { _Float16 h; unsigned short u; } cv;
    cv.h = (_Float16)f;
    return cv.u;
}

// sum of v over all 256 threads; red is float[4] shared scratch
__device__ __forceinline__ float block_sum256(float v, float* red, int tid) {
#pragma unroll
    for (int off = 32; off > 0; off >>= 1)
        v += __shfl_down(v, off, 64);
    if ((tid & 63) == 0) red[tid >> 6] = v;
    __syncthreads();
    float s = red[0] + red[1] + red[2] + red[3];
    __syncthreads();
    return s;
}

// ---------------- K1: MLP head (LN -> L1 relu -> L2 relu -> L3) ----------------
__global__ __launch_bounds__(256) void k_mlp_head(
    const float* __restrict__ cc, const float* __restrict__ ln0w, const float* __restrict__ ln0b,
    const float* __restrict__ W1, const float* __restrict__ b1,
    const float* __restrict__ W2, const float* __restrict__ b2,
    const float* __restrict__ W3, const float* __restrict__ b3,
    unsigned short* __restrict__ Mh)
{
    const int q = blockIdx.x, t = threadIdx.x;
    __shared__ float xs[CC], ys[CC];
    __shared__ float red[4];

    float v = cc[q * CC + t];
    float s = block_sum256(v, red, t);
    float m = s * (1.0f / CC);
    float d = v - m;
    float s2 = block_sum256(d * d, red, t);
    float rstd = rsqrtf(s2 * (1.0f / CC) + 1e-5f);
    xs[t] = d * rstd * ln0w[t] + ln0b[t];
    __syncthreads();

    float acc = 0.f;
    {
        const float* w = W1 + t * CC;
#pragma unroll 8
        for (int k = 0; k < CC; k += 4) {
            float4 wv = *(const float4*)(w + k);
            acc += xs[k] * wv.x + xs[k + 1] * wv.y + xs[k + 2] * wv.z + xs[k + 3] * wv.w;
        }
    }
    ys[t] = fmaxf(acc + b1[t], 0.f);
    __syncthreads();

    acc = 0.f;
    {
        const float* w = W2 + t * CC;
#pragma unroll 8
        for (int k = 0; k < CC; k += 4) {
            float4 wv = *(const float4*)(w + k);
            acc += ys[k] * wv.x + ys[k + 1] * wv.y + ys[k + 2] * wv.z + ys[k + 3] * wv.w;
        }
    }
    float x2 = fmaxf(acc + b2[t], 0.f);
    __syncthreads();
    xs[t] = x2;
    __syncthreads();

    acc = 0.f;
    {
        const float* w = W3 + t * CC;
#pragma unroll 8
        for (int k = 0; k < CC; k += 4) {
            float4 wv = *(const float4*)(w + k);
            acc += xs[k] * wv.x + xs[k + 1] * wv.y + xs[k + 2] * wv.z + xs[k + 3] * wv.w;
        }
    }
    Mh[q * CC + t] = f2h_bits(acc + b3[t]);
}

// ---------------- K2: logits = P @ M^T via f16 MFMA, + argmax ----------------
// K split in two halves of 128 -> 64 KB LDS -> 2 blocks/CU (cross-block overlap).
__global__ __launch_bounds__(256) void k_logits(
    const float* __restrict__ P, const unsigned short* __restrict__ Mh,
    float* __restrict__ out, int* __restrict__ assign, int N)
{
    __shared__ __align__(16) unsigned short Ms[128 * 128]; // 32 KB, swizzled
    __shared__ __align__(16) unsigned short Ps[128 * 128]; // 32 KB, swizzled
    const int tid = threadIdx.x;
    const int p0 = blockIdx.x << 7;
    const int w = tid >> 6, l = tid & 63;
    const int lr = l & 15, lg = l >> 4;

    f32x4 acc[2][8];
#pragma unroll
    for (int i = 0; i < 2; ++i)
#pragma unroll
        for (int j = 0; j < 8; ++j) acc[i][j] = (f32x4){0.f, 0.f, 0.f, 0.f};

    const char* PsB = reinterpret_cast<const char*>(Ps);
    const char* MsB = reinterpret_cast<const char*>(Ms);
    const int r0 = (w << 5) + lr;
    const int r1 = r0 + 16;
    const int sw0 = (lr & 7) << 4;

    for (int kh = 0; kh < 2; ++kh) {
        // stage M half: rows 0..127, cols [kh*128, kh*128+128)
#pragma unroll
        for (int it = 0; it < 8; ++it) {
            int i = tid + (it << 8);
            int row = i >> 4, ck = i & 15;
            uint4 vd = *reinterpret_cast<const uint4*>(Mh + (row << 8) + (kh << 7) + (ck << 3));
            int boff = (row << 8) + ((ck << 4) ^ ((row & 7) << 4));
            *reinterpret_cast<uint4*>(reinterpret_cast<char*>(Ms) + boff) = vd;
        }
        // stage P half, f32 -> f16
#pragma unroll
        for (int it = 0; it < 8; ++it) {
            int i = tid + (it << 8);
            int row = i >> 4, ck = i & 15;
            int p = p0 + row;
            float4 a = make_float4(0.f, 0.f, 0.f, 0.f), b = a;
            if (p < N) {
                const float4* src = reinterpret_cast<const float4*>(P + ((size_t)p << 8) + (kh << 7)) + (ck << 1);
                a = src[0]; b = src[1];
            }
            HU pu;
            pu.h[0] = (_Float16)a.x; pu.h[1] = (_Float16)a.y;
            pu.h[2] = (_Float16)a.z; pu.h[3] = (_Float16)a.w;
            pu.h[4] = (_Float16)b.x; pu.h[5] = (_Float16)b.y;
            pu.h[6] = (_Float16)b.z; pu.h[7] = (_Float16)b.w;
            int boff = (row << 8) + ((ck << 4) ^ ((row & 7) << 4));
            *reinterpret_cast<uint4*>(reinterpret_cast<char*>(Ps) + boff) = pu.u;
        }
        __syncthreads();

        __builtin_amdgcn_s_setprio(1);
#pragma unroll
        for (int kk = 0; kk < 4; ++kk) {
            const int bk = (kk << 6) + (lg << 4);
            half8 a0 = *reinterpret_cast<const half8*>(PsB + (r0 << 8) + (bk ^ sw0));
            half8 a1 = *reinterpret_cast<const half8*>(PsB + (r1 << 8) + (bk ^ sw0));
#pragma unroll
            for (int ct = 0; ct < 8; ++ct) {
                const int rb = (ct << 4) + lr;
                half8 bb = *reinterpret_cast<const half8*>(MsB + (rb << 8) + (bk ^ sw0));
                acc[0][ct] = __builtin_amdgcn_mfma_f32_16x16x32_f16(a0, bb, acc[0][ct], 0, 0, 0);
                acc[1][ct] = __builtin_amdgcn_mfma_f32_16x16x32_f16(a1, bb, acc[1][ct], 0, 0, 0);
            }
        }
        __builtin_amdgcn_s_setprio(0);
        __syncthreads();
    }

    // store logits + argmax (C/D: col = lane&15, row = (lane>>4)*4 + reg)
#pragma unroll
    for (int rt = 0; rt < 2; ++rt) {
#pragma unroll
        for (int j = 0; j < 4; ++j) {
            const int row = (w << 5) + (rt << 4) + (lg << 2) + j;
            const int p = p0 + row;
            float bv = -3.402823e38f; int bi = 0;
            if (p < N) {
                float* orow = out + ((size_t)p << 7);
#pragma unroll
                for (int ct = 0; ct < 8; ++ct) {
                    float vv = acc[rt][ct][j];
                    int cidx = (ct << 4) + lr;
                    orow[cidx] = vv;
                    if (vv > bv) { bv = vv; bi = cidx; }
                }
            }
#pragma unroll
            for (int msk = 1; msk < 16; msk <<= 1) {
                float ov = __shfl_xor(bv, msk, 64);
                int oi = __shfl_xor(bi, msk, 64);
                if (ov > bv || (ov == bv && oi < bi)) { bv = ov; bi = oi; }
            }
            if (lr == 0 && p < N) assign[p] = bi;
        }
    }
}

// ---------------- K3: segment sum, cluster-major, register accumulators --------
// grid = NGRP*HH blocks. Block (g = bid&15, h = bid>>4) owns clusters
// [g*8, g*8+8). The 128 waves of group g (over all h) split the point range
// into 1024-point chunks round-robin. Per chunk, per wave: ballot-compact
// matching indices into a wave-private LDS queue (no atomics), then walk the
// queue: whole wave loads one point row (float4/lane) and accumulates into
// register acc[8] selected by a scalarized branch. No LDS in the hot loop.
__global__ __launch_bounds__(256) void k_segsum(
    const float* __restrict__ P, const int* __restrict__ assign,
    float* __restrict__ partial, int N)
{
    __shared__ __align__(16) float redbuf[4][GG][CC];   // 32 KB
    int* queue = reinterpret_cast<int*>(redbuf);        // first 16 KB aliased as 4x1024 ints

    const int t = threadIdx.x;
    const int w = t >> 6, l = t & 63;
    const int g = blockIdx.x & (NGRP - 1);
    const int h = blockIdx.x >> 4;
    const int g0 = g << 3;
    const int wl = (h << 2) + w;           // 0..127: wave index within group
    const int qb = w << 10;                // per-wave queue base (1024 entries)

    float4 a0v = {0,0,0,0}, a1v = a0v, a2v = a0v, a3v = a0v;
    float4 a4v = a0v, a5v = a0v, a6v = a0v, a7v = a0v;

    const unsigned long long below = (1ull << l) - 1ull;
    const int nchunks = (N + 1023) >> 10;

    for (int c = wl; c < nchunks; c += NGRP * HH / NGRP * 4 * HH / HH) ; // (placeholder removed below)

    for (int c = wl; c < nchunks; c += 4 * HH) {
        const int cs = c << 10;
        const int ce = min(cs + 1024, N);
        int tail = 0;

        // ---- scan + compact (4 steps x 256 points) ----
#pragma unroll
        for (int s = 0; s < 4; ++s) {
            const int ib = cs + (s << 8) + (l << 2);
            int4 av = *reinterpret_cast<const int4*>(assign + ib); // may read past N within ws: masked below
#pragma unroll
            for (int j = 0; j < 4; ++j) {
                const int idx = ib + j;
                const int aj = (&av.x)[j];
                const unsigned ci = (unsigned)(aj - g0);
                const bool m = (ci < (unsigned)GG) && (idx < ce);
                const unsigned long long mask = __ballot(m);
                const int pos = tail + __popcll(mask & below);
                if (m) queue[qb + pos] = (idx << 3) | (int)ci;
                tail += __popcll(mask);
            }
        }

        // ---- walk queue: 8 rows per step, pipelined ----
        int i = 0;
        for (; i + 8 <= tail; i += 8) {
            int e[8]; float4 v[8];
#pragma unroll
            for (int k = 0; k < 8; ++k) e[k] = queue[qb + i + k];     // broadcast reads
#pragma unroll
            for (int k = 0; k < 8; ++k) {
                const int pp = e[k] >> 3;
                v[k] = *reinterpret_cast<const float4*>(P + (size_t)pp * CC + (l << 2));
            }
#pragma unroll
            for (int k = 0; k < 8; ++k) {
                const int ci = __builtin_amdgcn_readfirstlane(e[k] & 7);
                const float4 vk = v[k];
                if (ci == 0)      { a0v.x += vk.x; a0v.y += vk.y; a0v.z += vk.z; a0v.w += vk.w; }
                else if (ci == 1) { a1v.x += vk.x; a1v.y += vk.y; a1v.z += vk.z; a1v.w += vk.w; }
                else if (ci == 2) { a2v.x += vk.x; a2v.y += vk.y; a2v.z += vk.z; a2v.w += vk.w; }
                else if (ci == 3) { a3v.x += vk.x; a3v.y += vk.y; a3v.z += vk.z; a3v.w += vk.w; }
                else if (ci == 4) { a4v.x += vk.x; a4v.y += vk.y; a4v.z += vk.z; a4v.w += vk.w; }
                else if (ci == 5) { a5v.x += vk.x; a5v.y += vk.y; a5v.z += vk.z; a5v.w += vk.w; }
                else if (ci == 6) { a6v.x += vk.x; a6v.y += vk.y; a6v.z += vk.z; a6v.w += vk.w; }
                else              { a7v.x += vk.x; a7v.y += vk.y; a7v.z += vk.z; a7v.w += vk.w; }
            }
        }
        for (; i < tail; ++i) {
            const int e = queue[qb + i];
            const int pp = e >> 3;
            const float4 vk = *reinterpret_cast<const float4*>(P + (size_t)pp * CC + (l << 2));
            const int ci = __builtin_amdgcn_readfirstlane(e & 7);
            if (ci == 0)      { a0v.x += vk.x; a0v.y += vk.y; a0v.z += vk.z; a0v.w += vk.w; }
            else if (ci == 1) { a1v.x += vk.x; a1v.y += vk.y; a1v.z += vk.z; a1v.w += vk.w; }
            else if (ci == 2) { a2v.x += vk.x; a2v.y += vk.y; a2v.z += vk.z; a2v.w += vk.w; }
            else if (ci == 3) { a3v.x += vk.x; a3v.y += vk.y; a3v.z += vk.z; a3v.w += vk.w; }
            else if (ci == 4) { a4v.x += vk.x; a4v.y += vk.y; a4v.z += vk.z; a4v.w += vk.w; }
            else if (ci == 5) { a5v.x += vk.x; a5v.y += vk.y; a5v.z += vk.z; a5v.w += vk.w; }
            else if (ci == 6) { a6v.x += vk.x; a6v.y += vk.y; a6v.z += vk.z; a6v.w += vk.w; }
            else              { a7v.x += vk.x; a7v.y += vk.y; a7v.z += vk.z; a7v.w += vk.w; }
        }
    }

    // ---- cross-wave reduce (queue region is dead after this barrier) ----
    __syncthreads();
    {
        float4 av[GG] = {a0v, a1v, a2v, a3v, a4v, a5v, a6v, a7v};
#pragma unroll
        for (int ci = 0; ci < GG; ++ci)
            *reinterpret_cast<float4*>(&redbuf[w][ci][l << 2]) = av[ci];
    }
    __syncthreads();

    float* pout = partial + (((size_t)h * QQ) + g0) * CC;
#pragma unroll
    for (int ci = 0; ci < GG; ++ci) {
        float sm = redbuf[0][ci][t] + redbuf[1][ci][t] + redbuf[2][ci][t] + redbuf[3][ci][t];
        pout[(size_t)ci * CC + t] = sm;
    }
}

// ---------------- K4: reduce partials + bottleneck LN -> Wb -> LN, + residual --
__global__ __launch_bounds__(256) void k_bottleneck(
    const float* __restrict__ partial, int nparts,
    const float* __restrict__ lnb1w, const float* __restrict__ lnb1b,
    const float* __restrict__ Wb,
    const float* __restrict__ lnb2w, const float* __restrict__ lnb2b,
    const float* __restrict__ cc, float* __restrict__ out2)
{
    const int q = blockIdx.x, t = threadIdx.x;
    __shared__ float xs[CC];
    __shared__ float red[4];

    float v = 0.f;
    {
        const float* src = partial + (size_t)q * CC + t;
        int part = 0;
        for (; part + 7 < nparts; part += 8) {
            float s0 = src[(size_t)(part + 0) * (QQ * CC)];
            float s1 = src[(size_t)(part + 1) * (QQ * CC)];
            float s2 = src[(size_t)(part + 2) * (QQ * CC)];
            float s3 = src[(size_t)(part + 3) * (QQ * CC)];
            float s4 = src[(size_t)(part + 4) * (QQ * CC)];
            float s5 = src[(size_t)(part + 5) * (QQ * CC)];
            float s6 = src[(size_t)(part + 6) * (QQ * CC)];
            float s7 = src[(size_t)(part + 7) * (QQ * CC)];
            v += ((s0 + s1) + (s2 + s3)) + ((s4 + s5) + (s6 + s7));
        }
        for (; part < nparts; ++part)
            v += src[(size_t)part * (QQ * CC)];
    }

    float s = block_sum256(v, red, t);
    float m = s * (1.0f / CC);
    float d = v - m;
    float s2 = block_sum256(d * d, red, t);
    float rstd = rsqrtf(s2 * (1.0f / CC) + 1e-5f);
    xs[t] = d * rstd * lnb1w[t] + lnb1b[t];
    __syncthreads();

    float acc = 0.f;
    {
        const float* wp = Wb + t * CC;
#pragma unroll 8
        for (int k = 0; k < CC; k += 4) {
            float4 wv = *(const float4*)(wp + k);
            acc += xs[k] * wv.x + xs[k + 1] * wv.y + xs[k + 2] * wv.z + xs[k + 3] * wv.w;
        }
    }
    float zs = block_sum256(acc, red, t);
    float zm = zs * (1.0f / CC);
    float zd = acc - zm;
    float zs2 = block_sum256(zd * zd, red, t);
    float zr = rsqrtf(zs2 * (1.0f / CC) + 1e-5f);
    out2[q * CC + t] = cc[q * CC + t] + zd * zr * lnb2w[t] + lnb2b[t];
}

extern "C" void kernel_launch(void* const* d_in, const int* in_sizes, int n_in,
                              void* d_out, int out_size, void* d_ws, size_t ws_size,
                              hipStream_t stream) {
    const float* cc   = (const float*)d_in[0];
    const float* P    = (const float*)d_in[1];
    const float* ln0w = (const float*)d_in[2];
    const float* ln0b = (const float*)d_in[3];
    const float* W1   = (const float*)d_in[4];
    const float* b1   = (const float*)d_in[5];
    const float* W2   = (const float*)d_in[6];
    const float* b2   = (const float*)d_in[7];
    const float* W3   = (const float*)d_in[8];
    const float* b3   = (const float*)d_in[9];
    const float* lnb1w = (const float*)d_in[10];
    const float* lnb1b = (const float*)d_in[11];
    const float* Wb   = (const float*)d_in[12];
    const float* lnb2w = (const float*)d_in[13];
    const float* lnb2b = (const float*)d_in[14];

    const int N = in_sizes[1] / CC;

    char* ws = (char*)d_ws;
    unsigned short* Mh = (unsigned short*)ws;               // 65536 B
    size_t off = 65536;
    int* assign = (int*)(ws + off);                         // 4*N B
    off += ((size_t)4 * N + 4095) & ~(size_t)4095;          // partial MUST follow assign (scan tail reads past N)
    float* partial = (float*)(ws + off);                    // HH * 128 KB = 4 MB

    float* logits = (float*)d_out;                          // [N][128]
    float* out2 = (float*)d_out + (size_t)N * QQ;           // [128][256]

    k_mlp_head<<<QQ, 256, 0, stream>>>(cc, ln0w, ln0b, W1, b1, W2, b2, W3, b3, Mh);

    int nblk = (N + 127) >> 7;
    k_logits<<<nblk, 256, 0, stream>>>(P, Mh, logits, assign, N);

    k_segsum<<<NGRP * HH, 256, 0, stream>>>(P, assign, partial, N);

    k_bottleneck<<<QQ, 256, 0, stream>>>(partial, HH, lnb1w, lnb1b, Wb, lnb2w, lnb2b, cc, out2);
}

// Round 6
// 331.878 us; speedup vs baseline: 3.4268x; 1.0634x over previous
//
#include <hip/hip_runtime.h>
#include <hip/hip_bf16.h>

#define QQ 128
#define CC 256
#define GG 8      // clusters per group
#define NGRP 16   // 128/GG
#define HH 32     // range splits; segsum grid = NGRP*HH = 512

typedef __attribute__((ext_vector_type(8))) _Float16 half8;
typedef __attribute__((ext_vector_type(4))) float f32x4;

union HU { half8 h; uint4 u; };

__device__ __forceinline__ unsigned short f2h_bits(float f) {
    union { _Float16 h; unsigned short u; } cv;
    cv.h = (_Float16)f;
    return cv.u;
}

__device__ __forceinline__ half8 cvt8(float4 a, float4 b) {
    half8 h;
    h[0] = (_Float16)a.x; h[1] = (_Float16)a.y; h[2] = (_Float16)a.z; h[3] = (_Float16)a.w;
    h[4] = (_Float16)b.x; h[5] = (_Float16)b.y; h[6] = (_Float16)b.z; h[7] = (_Float16)b.w;
    return h;
}

// sum of v over all 256 threads; red is float[4] shared scratch
__device__ __forceinline__ float block_sum256(float v, float* red, int tid) {
#pragma unroll
    for (int off = 32; off > 0; off >>= 1)
        v += __shfl_down(v, off, 64);
    if ((tid & 63) == 0) red[tid >> 6] = v;
    __syncthreads();
    float s = red[0] + red[1] + red[2] + red[3];
    __syncthreads();
    return s;
}

// ---------------- K1: MLP head (LN -> L1 relu -> L2 relu -> L3) ----------------
__global__ __launch_bounds__(256) void k_mlp_head(
    const float* __restrict__ cc, const float* __restrict__ ln0w, const float* __restrict__ ln0b,
    const float* __restrict__ W1, const float* __restrict__ b1,
    const float* __restrict__ W2, const float* __restrict__ b2,
    const float* __restrict__ W3, const float* __restrict__ b3,
    unsigned short* __restrict__ Mh)
{
    const int q = blockIdx.x, t = threadIdx.x;
    __shared__ float xs[CC], ys[CC];
    __shared__ float red[4];

    float v = cc[q * CC + t];
    float s = block_sum256(v, red, t);
    float m = s * (1.0f / CC);
    float d = v - m;
    float s2 = block_sum256(d * d, red, t);
    float rstd = rsqrtf(s2 * (1.0f / CC) + 1e-5f);
    xs[t] = d * rstd * ln0w[t] + ln0b[t];
    __syncthreads();

    float acc = 0.f;
    {
        const float* w = W1 + t * CC;
#pragma unroll 8
        for (int k = 0; k < CC; k += 4) {
            float4 wv = *(const float4*)(w + k);
            acc += xs[k] * wv.x + xs[k + 1] * wv.y + xs[k + 2] * wv.z + xs[k + 3] * wv.w;
        }
    }
    ys[t] = fmaxf(acc + b1[t], 0.f);
    __syncthreads();

    acc = 0.f;
    {
        const float* w = W2 + t * CC;
#pragma unroll 8
        for (int k = 0; k < CC; k += 4) {
            float4 wv = *(const float4*)(w + k);
            acc += ys[k] * wv.x + ys[k + 1] * wv.y + ys[k + 2] * wv.z + ys[k + 3] * wv.w;
        }
    }
    float x2 = fmaxf(acc + b2[t], 0.f);
    __syncthreads();
    xs[t] = x2;
    __syncthreads();

    acc = 0.f;
    {
        const float* w = W3 + t * CC;
#pragma unroll 8
        for (int k = 0; k < CC; k += 4) {
            float4 wv = *(const float4*)(w + k);
            acc += xs[k] * wv.x + xs[k + 1] * wv.y + xs[k + 2] * wv.z + xs[k + 3] * wv.w;
        }
    }
    Mh[q * CC + t] = f2h_bits(acc + b3[t]);
}

// ---------------- K2: logits = P @ M^T via f16 MFMA, + argmax ----------------
// v3: A-fragments straight from global (row-major matches fragment layout;
// each row = one contiguous 128B segment). Only M in LDS (64 KB, staged once).
// 512 threads / 8 waves / 256 rows per block -> 2 blocks/CU, 16 waves/CU,
// zero barriers in the K-loop.
__global__ __launch_bounds__(512) void k_logits(
    const float* __restrict__ P, const unsigned short* __restrict__ Mh,
    float* __restrict__ out, int* __restrict__ assign, int N)
{
    __shared__ __align__(16) unsigned short Ms[QQ * CC]; // 64 KB, swizzled
    const int tid = threadIdx.x;
    const int p0 = blockIdx.x << 8;
    const int w = tid >> 6, l = tid & 63;
    const int lr = l & 15, lg = l >> 4;

    // stage M full (f16, swizzled): 4096 chunks of 16 B over 512 threads
#pragma unroll
    for (int it = 0; it < 8; ++it) {
        int i = tid + (it << 9);
        int row = i >> 5, ck = i & 31;
        uint4 vd = *(reinterpret_cast<const uint4*>(Mh + (row << 8)) + ck);
        int boff = (row << 9) + ((ck << 4) ^ ((row & 7) << 4));
        *reinterpret_cast<uint4*>(reinterpret_cast<char*>(Ms) + boff) = vd;
    }
    __syncthreads();

    f32x4 acc[2][8];
#pragma unroll
    for (int i = 0; i < 2; ++i)
#pragma unroll
        for (int j = 0; j < 8; ++j) acc[i][j] = (f32x4){0.f, 0.f, 0.f, 0.f};

    const char* MsB = reinterpret_cast<const char*>(Ms);
    const int sw0 = (lr & 7) << 4;
    const int kf = lg << 3; // f32 k-offset of this lane's 8-elem chunk

    // A source rows (clamped; rows >= N produce discarded C rows)
    const int ra0 = p0 + (w << 5) + lr;
    const int ra1 = ra0 + 16;
    const float* arow0 = P + (size_t)min(ra0, N - 1) * CC + kf;
    const float* arow1 = P + (size_t)min(ra1, N - 1) * CC + kf;

#pragma unroll
    for (int kk = 0; kk < 8; ++kk) {
        const float* pved0 = arow0 + (kk << 5);
        const float* pved1 = arow1 + (kk << 5);
        half8 a0 = cvt8(*reinterpret_cast<const float4*>(pved0),
                        *reinterpret_cast<const float4*>(pved0 + 4));
        half8 a1 = cvt8(*reinterpret_cast<const float4*>(pved1),
                        *reinterpret_cast<const float4*>(pved1 + 4));
        const int bk = (kk << 6) + (lg << 4);
#pragma unroll
        for (int ct = 0; ct < 8; ++ct) {
            const int rb = (ct << 4) + lr;
            half8 bb = *reinterpret_cast<const half8*>(MsB + (rb << 9) + (bk ^ sw0));
            acc[0][ct] = __builtin_amdgcn_mfma_f32_16x16x32_f16(a0, bb, acc[0][ct], 0, 0, 0);
            acc[1][ct] = __builtin_amdgcn_mfma_f32_16x16x32_f16(a1, bb, acc[1][ct], 0, 0, 0);
        }
    }

    // store logits + argmax (C/D: col = lane&15, row = (lane>>4)*4 + reg)
#pragma unroll
    for (int rt = 0; rt < 2; ++rt) {
#pragma unroll
        for (int j = 0; j < 4; ++j) {
            const int row = (w << 5) + (rt << 4) + (lg << 2) + j;
            const int p = p0 + row;
            float bv = -3.402823e38f; int bi = 0;
            if (p < N) {
                float* orow = out + ((size_t)p << 7);
#pragma unroll
                for (int ct = 0; ct < 8; ++ct) {
                    float vv = acc[rt][ct][j];
                    int cidx = (ct << 4) + lr;
                    orow[cidx] = vv;
                    if (vv > bv) { bv = vv; bi = cidx; }
                }
            }
#pragma unroll
            for (int msk = 1; msk < 16; msk <<= 1) {
                float ov = __shfl_xor(bv, msk, 64);
                int oi = __shfl_xor(bi, msk, 64);
                if (ov > bv || (ov == bv && oi < bi)) { bv = ov; bi = oi; }
            }
            if (lr == 0 && p < N) assign[p] = bi;
        }
    }
}

// ---------------- K3: segment sum, cluster-major, register accumulators --------
// grid = NGRP*HH blocks. Block (g = bid&15, h = bid>>4) owns clusters
// [g*8, g*8+8). Waves ballot-compact matching indices into a wave-private LDS
// queue (no atomics), then walk the queue: whole wave loads one point row
// (float4/lane, 1 KB coalesced) and accumulates into registers selected by a
// scalarized branch. No LDS in the hot loop.
__global__ __launch_bounds__(256) void k_segsum(
    const float* __restrict__ P, const int* __restrict__ assign,
    float* __restrict__ partial, int N)
{
    __shared__ __align__(16) float redbuf[4][GG][CC];   // 32 KB
    int* queue = reinterpret_cast<int*>(redbuf);        // first 16 KB aliased as 4x1024 ints

    const int t = threadIdx.x;
    const int w = t >> 6, l = t & 63;
    const int g = blockIdx.x & (NGRP - 1);
    const int h = blockIdx.x >> 4;
    const int g0 = g << 3;
    const int wl = (h << 2) + w;           // 0..127: wave index within group
    const int qb = w << 10;                // per-wave queue base (1024 entries)

    float4 a0v = {0,0,0,0}, a1v = a0v, a2v = a0v, a3v = a0v;
    float4 a4v = a0v, a5v = a0v, a6v = a0v, a7v = a0v;

    const unsigned long long below = (1ull << l) - 1ull;
    const int nchunks = (N + 1023) >> 10;

    for (int c = wl; c < nchunks; c += 4 * HH) {
        const int cs = c << 10;
        const int ce = min(cs + 1024, N);
        int tail = 0;

        // ---- scan + compact (4 steps x 256 points) ----
#pragma unroll
        for (int s = 0; s < 4; ++s) {
            const int ib = cs + (s << 8) + (l << 2);
            int4 av = *reinterpret_cast<const int4*>(assign + ib); // may read past N within ws: masked below
#pragma unroll
            for (int j = 0; j < 4; ++j) {
                const int idx = ib + j;
                const int aj = (&av.x)[j];
                const unsigned ci = (unsigned)(aj - g0);
                const bool m = (ci < (unsigned)GG) && (idx < ce);
                const unsigned long long mask = __ballot(m);
                const int pos = tail + __popcll(mask & below);
                if (m) queue[qb + pos] = (idx << 3) | (int)ci;
                tail += __popcll(mask);
            }
        }

        // ---- walk queue: 8 rows per step, pipelined ----
        int i = 0;
        for (; i + 8 <= tail; i += 8) {
            int e[8]; float4 v[8];
#pragma unroll
            for (int k = 0; k < 8; ++k) e[k] = queue[qb + i + k];     // broadcast reads
#pragma unroll
            for (int k = 0; k < 8; ++k) {
                const int pp = e[k] >> 3;
                v[k] = *reinterpret_cast<const float4*>(P + (size_t)pp * CC + (l << 2));
            }
#pragma unroll
            for (int k = 0; k < 8; ++k) {
                const int ci = __builtin_amdgcn_readfirstlane(e[k] & 7);
                const float4 vk = v[k];
                if (ci == 0)      { a0v.x += vk.x; a0v.y += vk.y; a0v.z += vk.z; a0v.w += vk.w; }
                else if (ci == 1) { a1v.x += vk.x; a1v.y += vk.y; a1v.z += vk.z; a1v.w += vk.w; }
                else if (ci == 2) { a2v.x += vk.x; a2v.y += vk.y; a2v.z += vk.z; a2v.w += vk.w; }
                else if (ci == 3) { a3v.x += vk.x; a3v.y += vk.y; a3v.z += vk.z; a3v.w += vk.w; }
                else if (ci == 4) { a4v.x += vk.x; a4v.y += vk.y; a4v.z += vk.z; a4v.w += vk.w; }
                else if (ci == 5) { a5v.x += vk.x; a5v.y += vk.y; a5v.z += vk.z; a5v.w += vk.w; }
                else if (ci == 6) { a6v.x += vk.x; a6v.y += vk.y; a6v.z += vk.z; a6v.w += vk.w; }
                else              { a7v.x += vk.x; a7v.y += vk.y; a7v.z += vk.z; a7v.w += vk.w; }
            }
        }
        for (; i < tail; ++i) {
            const int e = queue[qb + i];
            const int pp = e >> 3;
            const float4 vk = *reinterpret_cast<const float4*>(P + (size_t)pp * CC + (l << 2));
            const int ci = __builtin_amdgcn_readfirstlane(e & 7);
            if (ci == 0)      { a0v.x += vk.x; a0v.y += vk.y; a0v.z += vk.z; a0v.w += vk.w; }
            else if (ci == 1) { a1v.x += vk.x; a1v.y += vk.y; a1v.z += vk.z; a1v.w += vk.w; }
            else if (ci == 2) { a2v.x += vk.x; a2v.y += vk.y; a2v.z += vk.z; a2v.w += vk.w; }
            else if (ci == 3) { a3v.x += vk.x; a3v.y += vk.y; a3v.z += vk.z; a3v.w += vk.w; }
            else if (ci == 4) { a4v.x += vk.x; a4v.y += vk.y; a4v.z += vk.z; a4v.w += vk.w; }
            else if (ci == 5) { a5v.x += vk.x; a5v.y += vk.y; a5v.z += vk.z; a5v.w += vk.w; }
            else if (ci == 6) { a6v.x += vk.x; a6v.y += vk.y; a6v.z += vk.z; a6v.w += vk.w; }
            else              { a7v.x += vk.x; a7v.y += vk.y; a7v.z += vk.z; a7v.w += vk.w; }
        }
    }

    // ---- cross-wave reduce (queue region is dead after this barrier) ----
    __syncthreads();
    {
        float4 av[GG] = {a0v, a1v, a2v, a3v, a4v, a5v, a6v, a7v};
#pragma unroll
        for (int ci = 0; ci < GG; ++ci)
            *reinterpret_cast<float4*>(&redbuf[w][ci][l << 2]) = av[ci];
    }
    __syncthreads();

    float* pout = partial + (((size_t)h * QQ) + g0) * CC;
#pragma unroll
    for (int ci = 0; ci < GG; ++ci) {
        float sm = redbuf[0][ci][t] + redbuf[1][ci][t] + redbuf[2][ci][t] + redbuf[3][ci][t];
        pout[(size_t)ci * CC + t] = sm;
    }
}

// ---------------- K4: reduce partials + bottleneck LN -> Wb -> LN, + residual --
__global__ __launch_bounds__(256) void k_bottleneck(
    const float* __restrict__ partial, int nparts,
    const float* __restrict__ lnb1w, const float* __restrict__ lnb1b,
    const float* __restrict__ Wb,
    const float* __restrict__ lnb2w, const float* __restrict__ lnb2b,
    const float* __restrict__ cc, float* __restrict__ out2)
{
    const int q = blockIdx.x, t = threadIdx.x;
    __shared__ float xs[CC];
    __shared__ float red[4];

    float v = 0.f;
    {
        const float* src = partial + (size_t)q * CC + t;
        int part = 0;
        for (; part + 7 < nparts; part += 8) {
            float s0 = src[(size_t)(part + 0) * (QQ * CC)];
            float s1 = src[(size_t)(part + 1) * (QQ * CC)];
            float s2 = src[(size_t)(part + 2) * (QQ * CC)];
            float s3 = src[(size_t)(part + 3) * (QQ * CC)];
            float s4 = src[(size_t)(part + 4) * (QQ * CC)];
            float s5 = src[(size_t)(part + 5) * (QQ * CC)];
            float s6 = src[(size_t)(part + 6) * (QQ * CC)];
            float s7 = src[(size_t)(part + 7) * (QQ * CC)];
            v += ((s0 + s1) + (s2 + s3)) + ((s4 + s5) + (s6 + s7));
        }
        for (; part < nparts; ++part)
            v += src[(size_t)part * (QQ * CC)];
    }

    float s = block_sum256(v, red, t);
    float m = s * (1.0f / CC);
    float d = v - m;
    float s2 = block_sum256(d * d, red, t);
    float rstd = rsqrtf(s2 * (1.0f / CC) + 1e-5f);
    xs[t] = d * rstd * lnb1w[t] + lnb1b[t];
    __syncthreads();

    float acc = 0.f;
    {
        const float* wp = Wb + t * CC;
#pragma unroll 8
        for (int k = 0; k < CC; k += 4) {
            float4 wv = *(const float4*)(wp + k);
            acc += xs[k] * wv.x + xs[k + 1] * wv.y + xs[k + 2] * wv.z + xs[k + 3] * wv.w;
        }
    }
    float zs = block_sum256(acc, red, t);
    float zm = zs * (1.0f / CC);
    float zd = acc - zm;
    float zs2 = block_sum256(zd * zd, red, t);
    float zr = rsqrtf(zs2 * (1.0f / CC) + 1e-5f);
    out2[q * CC + t] = cc[q * CC + t] + zd * zr * lnb2w[t] + lnb2b[t];
}

extern "C" void kernel_launch(void* const* d_in, const int* in_sizes, int n_in,
                              void* d_out, int out_size, void* d_ws, size_t ws_size,
                              hipStream_t stream) {
    const float* cc   = (const float*)d_in[0];
    const float* P    = (const float*)d_in[1];
    const float* ln0w = (const float*)d_in[2];
    const float* ln0b = (const float*)d_in[3];
    const float* W1   = (const float*)d_in[4];
    const float* b1   = (const float*)d_in[5];
    const float* W2   = (const float*)d_in[6];
    const float* b2   = (const float*)d_in[7];
    const float* W3   = (const float*)d_in[8];
    const float* b3   = (const float*)d_in[9];
    const float* lnb1w = (const float*)d_in[10];
    const float* lnb1b = (const float*)d_in[11];
    const float* Wb   = (const float*)d_in[12];
    const float* lnb2w = (const float*)d_in[13];
    const float* lnb2b = (const float*)d_in[14];

    const int N = in_sizes[1] / CC;

    char* ws = (char*)d_ws;
    unsigned short* Mh = (unsigned short*)ws;               // 65536 B
    size_t off = 65536;
    int* assign = (int*)(ws + off);                         // 4*N B
    off += ((size_t)4 * N + 4095) & ~(size_t)4095;          // partial MUST follow assign (scan tail reads past N)
    float* partial = (float*)(ws + off);                    // HH * 128 KB = 4 MB

    float* logits = (float*)d_out;                          // [N][128]
    float* out2 = (float*)d_out + (size_t)N * QQ;           // [128][256]

    k_mlp_head<<<QQ, 256, 0, stream>>>(cc, ln0w, ln0b, W1, b1, W2, b2, W3, b3, Mh);

    int nblk = (N + 255) >> 8;
    k_logits<<<nblk, 512, 0, stream>>>(P, Mh, logits, assign, N);

    k_segsum<<<NGRP * HH, 256, 0, stream>>>(P, assign, partial, N);

    k_bottleneck<<<QQ, 256, 0, stream>>>(partial, HH, lnb1w, lnb1b, Wb, lnb2w, lnb2b, cc, out2);
}

// Round 8
// 329.609 us; speedup vs baseline: 3.4504x; 1.0069x over previous
//
#include <hip/hip_runtime.h>
#include <hip/hip_bf16.h>

#define QQ 128
#define CC 256
#define GG 8      // clusters per group
#define NGRP 16   // 128/GG
#define HH 32     // range splits; segsum grid = NGRP*HH = 512

typedef __attribute__((ext_vector_type(8))) _Float16 half8;
typedef __attribute__((ext_vector_type(4))) float f32x4;
typedef __attribute__((ext_vector_type(4))) int i32x4;

__device__ __forceinline__ unsigned short f2h_bits(float f) {
    union { _Float16 h; unsigned short u; } cv;
    cv.h = (_Float16)f;
    return cv.u;
}

__device__ __forceinline__ half8 cvt8(f32x4 a, f32x4 b) {
    half8 h;
    h[0] = (_Float16)a.x; h[1] = (_Float16)a.y; h[2] = (_Float16)a.z; h[3] = (_Float16)a.w;
    h[4] = (_Float16)b.x; h[5] = (_Float16)b.y; h[6] = (_Float16)b.z; h[7] = (_Float16)b.w;
    return h;
}

// sum of v over all 256 threads; red is float[4] shared scratch
__device__ __forceinline__ float block_sum256(float v, float* red, int tid) {
#pragma unroll
    for (int off = 32; off > 0; off >>= 1)
        v += __shfl_down(v, off, 64);
    if ((tid & 63) == 0) red[tid >> 6] = v;
    __syncthreads();
    float s = red[0] + red[1] + red[2] + red[3];
    __syncthreads();
    return s;
}

// ---------------- K1: MLP head (LN -> L1 relu -> L2 relu -> L3) ----------------
__global__ __launch_bounds__(256) void k_mlp_head(
    const float* __restrict__ cc, const float* __restrict__ ln0w, const float* __restrict__ ln0b,
    const float* __restrict__ W1, const float* __restrict__ b1,
    const float* __restrict__ W2, const float* __restrict__ b2,
    const float* __restrict__ W3, const float* __restrict__ b3,
    unsigned short* __restrict__ Mh)
{
    const int q = blockIdx.x, t = threadIdx.x;
    __shared__ float xs[CC], ys[CC];
    __shared__ float red[4];

    float v = cc[q * CC + t];
    float s = block_sum256(v, red, t);
    float m = s * (1.0f / CC);
    float d = v - m;
    float s2 = block_sum256(d * d, red, t);
    float rstd = rsqrtf(s2 * (1.0f / CC) + 1e-5f);
    xs[t] = d * rstd * ln0w[t] + ln0b[t];
    __syncthreads();

    float acc = 0.f;
    {
        const float* w = W1 + t * CC;
#pragma unroll 8
        for (int k = 0; k < CC; k += 4) {
            f32x4 wv = *(const f32x4*)(w + k);
            acc += xs[k] * wv.x + xs[k + 1] * wv.y + xs[k + 2] * wv.z + xs[k + 3] * wv.w;
        }
    }
    ys[t] = fmaxf(acc + b1[t], 0.f);
    __syncthreads();

    acc = 0.f;
    {
        const float* w = W2 + t * CC;
#pragma unroll 8
        for (int k = 0; k < CC; k += 4) {
            f32x4 wv = *(const f32x4*)(w + k);
            acc += ys[k] * wv.x + ys[k + 1] * wv.y + ys[k + 2] * wv.z + ys[k + 3] * wv.w;
        }
    }
    float x2 = fmaxf(acc + b2[t], 0.f);
    __syncthreads();
    xs[t] = x2;
    __syncthreads();

    acc = 0.f;
    {
        const float* w = W3 + t * CC;
#pragma unroll 8
        for (int k = 0; k < CC; k += 4) {
            f32x4 wv = *(const f32x4*)(w + k);
            acc += xs[k] * wv.x + xs[k + 1] * wv.y + xs[k + 2] * wv.z + xs[k + 3] * wv.w;
        }
    }
    Mh[q * CC + t] = f2h_bits(acc + b3[t]);
}

// ---------------- K2: logits = P @ M^T via f16 MFMA, + argmax ----------------
// v4: v3 + epilogue LDS-transpose -> dwordx4 nontemporal stores (128B granule,
// no L2 pollution), nontemporal A loads. LDS 64+16=80 KB -> 2 blocks/CU.
__global__ __launch_bounds__(512) void k_logits(
    const float* __restrict__ P, const unsigned short* __restrict__ Mh,
    float* __restrict__ out, int* __restrict__ assign, int N)
{
    __shared__ __align__(16) unsigned short Ms[QQ * CC]; // 64 KB, swizzled
    __shared__ __align__(16) float eps[8][4][128];       // 16 KB, wave-private transpose slots
    const int tid = threadIdx.x;
    const int p0 = blockIdx.x << 8;
    const int w = tid >> 6, l = tid & 63;
    const int lr = l & 15, lg = l >> 4;

    // stage M full (f16, swizzled): 4096 chunks of 16 B over 512 threads
#pragma unroll
    for (int it = 0; it < 8; ++it) {
        int i = tid + (it << 9);
        int row = i >> 5, ck = i & 31;
        uint4 vd = *(reinterpret_cast<const uint4*>(Mh + (row << 8)) + ck);
        int boff = (row << 9) + ((ck << 4) ^ ((row & 7) << 4));
        *reinterpret_cast<uint4*>(reinterpret_cast<char*>(Ms) + boff) = vd;
    }
    __syncthreads();

    f32x4 acc[2][8];
#pragma unroll
    for (int i = 0; i < 2; ++i)
#pragma unroll
        for (int j = 0; j < 8; ++j) acc[i][j] = (f32x4){0.f, 0.f, 0.f, 0.f};

    const char* MsB = reinterpret_cast<const char*>(Ms);
    const int sw0 = (lr & 7) << 4;
    const int kf = lg << 3; // f32 k-offset of this lane's 8-elem chunk

    // A source rows (clamped; rows >= N produce discarded C rows)
    const int ra0 = p0 + (w << 5) + lr;
    const int ra1 = ra0 + 16;
    const float* arow0 = P + (size_t)min(ra0, N - 1) * CC + kf;
    const float* arow1 = P + (size_t)min(ra1, N - 1) * CC + kf;

#pragma unroll
    for (int kk = 0; kk < 8; ++kk) {
        const float* pved0 = arow0 + (kk << 5);
        const float* pved1 = arow1 + (kk << 5);
        f32x4 a0lo = __builtin_nontemporal_load(reinterpret_cast<const f32x4*>(pved0));
        f32x4 a0hi = __builtin_nontemporal_load(reinterpret_cast<const f32x4*>(pved0 + 4));
        f32x4 a1lo = __builtin_nontemporal_load(reinterpret_cast<const f32x4*>(pved1));
        f32x4 a1hi = __builtin_nontemporal_load(reinterpret_cast<const f32x4*>(pved1 + 4));
        half8 a0 = cvt8(a0lo, a0hi);
        half8 a1 = cvt8(a1lo, a1hi);
        const int bk = (kk << 6) + (lg << 4);
#pragma unroll
        for (int ct = 0; ct < 8; ++ct) {
            const int rb = (ct << 4) + lr;
            half8 bb = *reinterpret_cast<const half8*>(MsB + (rb << 9) + (bk ^ sw0));
            acc[0][ct] = __builtin_amdgcn_mfma_f32_16x16x32_f16(a0, bb, acc[0][ct], 0, 0, 0);
            acc[1][ct] = __builtin_amdgcn_mfma_f32_16x16x32_f16(a1, bb, acc[1][ct], 0, 0, 0);
        }
    }

    // epilogue: argmax on registers, then LDS transpose -> vector stores.
    // C/D layout: col = ct*16 + lr, row = (w<<5) + rt*16 + lg*4 + j.
    float* myeps = &eps[w][0][0];
#pragma unroll
    for (int rt = 0; rt < 2; ++rt) {
#pragma unroll
        for (int j = 0; j < 4; ++j) {
            // argmax over this lane's 8 cols, then 16-lane reduce
            float bv = -3.402823e38f; int bi = 0;
#pragma unroll
            for (int ct = 0; ct < 8; ++ct) {
                float vv = acc[rt][ct][j];
                int cidx = (ct << 4) + lr;
                if (vv > bv) { bv = vv; bi = cidx; }
                myeps[(lg << 7) + cidx] = vv;   // transpose slot [lg][cidx]
            }
#pragma unroll
            for (int msk = 1; msk < 16; msk <<= 1) {
                float ov = __shfl_xor(bv, msk, 64);
                int oi = __shfl_xor(bi, msk, 64);
                if (ov > bv || (ov == bv && oi < bi)) { bv = ov; bi = oi; }
            }
            {
                const int rowm = (w << 5) + (rt << 4) + (lg << 2) + j;
                const int pm = p0 + rowm;
                if (lr == 0 && pm < N) assign[pm] = bi;
            }
            // read back row-major: lane l -> row (l>>4), cols (l&15)*8..+7
            f32x4 v0 = *reinterpret_cast<const f32x4*>(&myeps[((l >> 4) << 7) + ((l & 15) << 3)]);
            f32x4 v1 = *reinterpret_cast<const f32x4*>(&myeps[((l >> 4) << 7) + ((l & 15) << 3) + 4]);
            const int row = (w << 5) + (rt << 4) + ((l >> 4) << 2) + j;
            const int p = p0 + row;
            if (p < N) {
                float* dst = out + ((size_t)p << 7) + ((l & 15) << 3);
                __builtin_nontemporal_store(v0, reinterpret_cast<f32x4*>(dst));
                __builtin_nontemporal_store(v1, reinterpret_cast<f32x4*>(dst + 4));
            }
        }
    }
}

// ---------------- K3: segment sum, cluster-major, register accumulators --------
// grid = NGRP*HH blocks. Block (g = bid&15, h = bid>>4) owns clusters
// [g*8, g*8+8). Waves ballot-compact matching indices into a wave-private LDS
// queue (no atomics), then walk the queue: whole wave loads one point row
// (f32x4/lane, 1 KB coalesced, nontemporal) and accumulates into registers
// selected by a scalarized branch. No LDS in the hot loop.
__global__ __launch_bounds__(256) void k_segsum(
    const float* __restrict__ P, const int* __restrict__ assign,
    float* __restrict__ partial, int N)
{
    __shared__ __align__(16) float redbuf[4][GG][CC];   // 32 KB
    int* queue = reinterpret_cast<int*>(redbuf);        // first 16 KB aliased as 4x1024 ints

    const int t = threadIdx.x;
    const int w = t >> 6, l = t & 63;
    const int g = blockIdx.x & (NGRP - 1);
    const int h = blockIdx.x >> 4;
    const int g0 = g << 3;
    const int wl = (h << 2) + w;           // 0..127: wave index within group
    const int qb = w << 10;                // per-wave queue base (1024 entries)

    f32x4 a0v = {0,0,0,0}, a1v = a0v, a2v = a0v, a3v = a0v;
    f32x4 a4v = a0v, a5v = a0v, a6v = a0v, a7v = a0v;

    const unsigned long long below = (1ull << l) - 1ull;
    const int nchunks = (N + 1023) >> 10;

    for (int c = wl; c < nchunks; c += 4 * HH) {
        const int cs = c << 10;
        const int ce = min(cs + 1024, N);
        int tail = 0;

        // ---- scan + compact (4 steps x 256 points) ----
#pragma unroll
        for (int s = 0; s < 4; ++s) {
            const int ib = cs + (s << 8) + (l << 2);
            i32x4 av = *reinterpret_cast<const i32x4*>(assign + ib); // may read past N within ws: masked below
#pragma unroll
            for (int j = 0; j < 4; ++j) {
                const int idx = ib + j;
                const int aj = av[j];
                const unsigned ci = (unsigned)(aj - g0);
                const bool m = (ci < (unsigned)GG) && (idx < ce);
                const unsigned long long mask = __ballot(m);
                const int pos = tail + __popcll(mask & below);
                if (m) queue[qb + pos] = (idx << 3) | (int)ci;
                tail += __popcll(mask);
            }
        }

        // ---- walk queue: 8 rows per step, pipelined ----
        int i = 0;
        for (; i + 8 <= tail; i += 8) {
            int e[8]; f32x4 v[8];
#pragma unroll
            for (int k = 0; k < 8; ++k) e[k] = queue[qb + i + k];     // broadcast reads
#pragma unroll
            for (int k = 0; k < 8; ++k) {
                const int pp = e[k] >> 3;
                v[k] = __builtin_nontemporal_load(
                    reinterpret_cast<const f32x4*>(P + (size_t)pp * CC + (l << 2)));
            }
#pragma unroll
            for (int k = 0; k < 8; ++k) {
                const int ci = __builtin_amdgcn_readfirstlane(e[k] & 7);
                const f32x4 vk = v[k];
                if (ci == 0)      a0v += vk;
                else if (ci == 1) a1v += vk;
                else if (ci == 2) a2v += vk;
                else if (ci == 3) a3v += vk;
                else if (ci == 4) a4v += vk;
                else if (ci == 5) a5v += vk;
                else if (ci == 6) a6v += vk;
                else              a7v += vk;
            }
        }
        for (; i < tail; ++i) {
            const int e = queue[qb + i];
            const int pp = e >> 3;
            const f32x4 vk = __builtin_nontemporal_load(
                reinterpret_cast<const f32x4*>(P + (size_t)pp * CC + (l << 2)));
            const int ci = __builtin_amdgcn_readfirstlane(e & 7);
            if (ci == 0)      a0v += vk;
            else if (ci == 1) a1v += vk;
            else if (ci == 2) a2v += vk;
            else if (ci == 3) a3v += vk;
            else if (ci == 4) a4v += vk;
            else if (ci == 5) a5v += vk;
            else if (ci == 6) a6v += vk;
            else              a7v += vk;
        }
    }

    // ---- cross-wave reduce (queue region is dead after this barrier) ----
    __syncthreads();
    {
        f32x4 av[GG] = {a0v, a1v, a2v, a3v, a4v, a5v, a6v, a7v};
#pragma unroll
        for (int ci = 0; ci < GG; ++ci)
            *reinterpret_cast<f32x4*>(&redbuf[w][ci][l << 2]) = av[ci];
    }
    __syncthreads();

    float* pout = partial + (((size_t)h * QQ) + g0) * CC;
#pragma unroll
    for (int ci = 0; ci < GG; ++ci) {
        float sm = redbuf[0][ci][t] + redbuf[1][ci][t] + redbuf[2][ci][t] + redbuf[3][ci][t];
        pout[(size_t)ci * CC + t] = sm;
    }
}

// ---------------- K4: reduce partials + bottleneck LN -> Wb -> LN, + residual --
__global__ __launch_bounds__(256) void k_bottleneck(
    const float* __restrict__ partial, int nparts,
    const float* __restrict__ lnb1w, const float* __restrict__ lnb1b,
    const float* __restrict__ Wb,
    const float* __restrict__ lnb2w, const float* __restrict__ lnb2b,
    const float* __restrict__ cc, float* __restrict__ out2)
{
    const int q = blockIdx.x, t = threadIdx.x;
    __shared__ float xs[CC];
    __shared__ float red[4];

    float v = 0.f;
    {
        const float* src = partial + (size_t)q * CC + t;
        int part = 0;
        for (; part + 7 < nparts; part += 8) {
            float s0 = src[(size_t)(part + 0) * (QQ * CC)];
            float s1 = src[(size_t)(part + 1) * (QQ * CC)];
            float s2 = src[(size_t)(part + 2) * (QQ * CC)];
            float s3 = src[(size_t)(part + 3) * (QQ * CC)];
            float s4 = src[(size_t)(part + 4) * (QQ * CC)];
            float s5 = src[(size_t)(part + 5) * (QQ * CC)];
            float s6 = src[(size_t)(part + 6) * (QQ * CC)];
            float s7 = src[(size_t)(part + 7) * (QQ * CC)];
            v += ((s0 + s1) + (s2 + s3)) + ((s4 + s5) + (s6 + s7));
        }
        for (; part < nparts; ++part)
            v += src[(size_t)part * (QQ * CC)];
    }

    float s = block_sum256(v, red, t);
    float m = s * (1.0f / CC);
    float d = v - m;
    float s2 = block_sum256(d * d, red, t);
    float rstd = rsqrtf(s2 * (1.0f / CC) + 1e-5f);
    xs[t] = d * rstd * lnb1w[t] + lnb1b[t];
    __syncthreads();

    float acc = 0.f;
    {
        const float* wp = Wb + t * CC;
#pragma unroll 8
        for (int k = 0; k < CC; k += 4) {
            f32x4 wv = *(const f32x4*)(wp + k);
            acc += xs[k] * wv.x + xs[k + 1] * wv.y + xs[k + 2] * wv.z + xs[k + 3] * wv.w;
        }
    }
    float zs = block_sum256(acc, red, t);
    float zm = zs * (1.0f / CC);
    float zd = acc - zm;
    float zs2 = block_sum256(zd * zd, red, t);
    float zr = rsqrtf(zs2 * (1.0f / CC) + 1e-5f);
    out2[q * CC + t] = cc[q * CC + t] + zd * zr * lnb2w[t] + lnb2b[t];
}

extern "C" void kernel_launch(void* const* d_in, const int* in_sizes, int n_in,
                              void* d_out, int out_size, void* d_ws, size_t ws_size,
                              hipStream_t stream) {
    const float* cc   = (const float*)d_in[0];
    const float* P    = (const float*)d_in[1];
    const float* ln0w = (const float*)d_in[2];
    const float* ln0b = (const float*)d_in[3];
    const float* W1   = (const float*)d_in[4];
    const float* b1   = (const float*)d_in[5];
    const float* W2   = (const float*)d_in[6];
    const float* b2   = (const float*)d_in[7];
    const float* W3   = (const float*)d_in[8];
    const float* b3   = (const float*)d_in[9];
    const float* lnb1w = (const float*)d_in[10];
    const float* lnb1b = (const float*)d_in[11];
    const float* Wb   = (const float*)d_in[12];
    const float* lnb2w = (const float*)d_in[13];
    const float* lnb2b = (const float*)d_in[14];

    const int N = in_sizes[1] / CC;

    char* ws = (char*)d_ws;
    unsigned short* Mh = (unsigned short*)ws;               // 65536 B
    size_t off = 65536;
    int* assign = (int*)(ws + off);                         // 4*N B
    off += ((size_t)4 * N + 4095) & ~(size_t)4095;          // partial MUST follow assign (scan tail reads past N)
    float* partial = (float*)(ws + off);                    // HH * 128 KB = 4 MB

    float* logits = (float*)d_out;                          // [N][128]
    float* out2 = (float*)d_out + (size_t)N * QQ;           // [128][256]

    k_mlp_head<<<QQ, 256, 0, stream>>>(cc, ln0w, ln0b, W1, b1, W2, b2, W3, b3, Mh);

    int nblk = (N + 255) >> 8;
    k_logits<<<nblk, 512, 0, stream>>>(P, Mh, logits, assign, N);

    k_segsum<<<NGRP * HH, 256, 0, stream>>>(P, assign, partial, N);

    k_bottleneck<<<QQ, 256, 0, stream>>>(partial, HH, lnb1w, lnb1b, Wb, lnb2w, lnb2b, cc, out2);
}